// Round 1
// baseline (833.446 us; speedup 1.0000x reference)
//
#include <hip/hip_runtime.h>

#define EPSV 1e-5f

__device__ __forceinline__ float relu(float x) { return fmaxf(x, 0.f); }

// ---------------- depthwise 3x3, pad 1 ----------------
// If BNIN: input element x -> relu(x*sc[c] + sh[c]) before convolving.
template<int S, int IHW, int OHW, bool BNIN>
__global__ __launch_bounds__(256) void dwconv_k(
    const float* __restrict__ in, float* __restrict__ out,
    const float* __restrict__ w9, const float* __restrict__ bias,
    const float* __restrict__ sc, const float* __restrict__ sh,
    int N, int C)
{
    const int OP = OHW * OHW;
    int idx = blockIdx.x * 256 + threadIdx.x;
    int total = N * C * OP;
    if (idx >= total) return;
    int ow = idx % OHW;
    int oh = (idx / OHW) % OHW;
    int c  = (idx / OP) % C;
    int n  = idx / (OP * C);
    const float* ip = in + (n * C + c) * (IHW * IHW);
    float scv = 1.f, shv = 0.f;
    if (BNIN) { scv = sc[c]; shv = sh[c]; }
    float acc = bias[c];
#pragma unroll
    for (int kh = 0; kh < 3; kh++) {
        int ih = oh * S + kh - 1;
        if ((unsigned)ih >= (unsigned)IHW) continue;
#pragma unroll
        for (int kw = 0; kw < 3; kw++) {
            int iw = ow * S + kw - 1;
            if ((unsigned)iw >= (unsigned)IHW) continue;
            float x = ip[ih * IHW + iw];
            if (BNIN) x = relu(fmaf(x, scv, shv));
            acc = fmaf(w9[c * 9 + kh * 3 + kw], x, acc);
        }
    }
    out[idx] = acc;
}

// ---------------- pointwise 1x1 conv ----------------
// Applies BN+ReLU (sc/sh) to input channels on load, writes raw conv+bias.
template<int CIN, int COUT, int HW>
__global__ __launch_bounds__(256) void pwconv_k(
    const float* __restrict__ in, float* __restrict__ out,
    const float* __restrict__ w, const float* __restrict__ bias,
    const float* __restrict__ sc, const float* __restrict__ sh,
    int N)
{
    int pix = blockIdx.x * 256 + threadIdx.x;
    if (pix >= N * HW) return;
    int n = pix / HW;
    int p = pix % HW;
    const float* ip = in + n * CIN * HW + p;
    float xin[CIN];
#pragma unroll
    for (int ci = 0; ci < CIN; ci++)
        xin[ci] = relu(fmaf(ip[ci * HW], sc[ci], sh[ci]));
    float* op = out + n * COUT * HW + p;
    for (int co = 0; co < COUT; co++) {
        float acc = bias[co];
#pragma unroll
        for (int ci = 0; ci < CIN; ci++)
            acc = fmaf(w[co * CIN + ci], xin[ci], acc);
        op[co * HW] = acc;
    }
}

// ---------------- per-channel sum / sumsq over (N, plane) ----------------
__global__ __launch_bounds__(256) void stats_k(
    const float* __restrict__ t, float* __restrict__ gsum, float* __restrict__ gsq,
    int C, int plane, int N, int nsb)
{
    int c = blockIdx.x;
    int sb = blockIdx.y;
    float s = 0.f, q = 0.f;
    for (int n = 0; n < N; n++) {
        const float* pl = t + (n * C + c) * plane;
        for (int p = sb * 256 + threadIdx.x; p < plane; p += 256 * nsb) {
            float v = pl[p];
            s += v;
            q = fmaf(v, v, q);
        }
    }
    int lane = threadIdx.x & 63, wid = threadIdx.x >> 6;
#pragma unroll
    for (int o = 32; o; o >>= 1) { s += __shfl_down(s, o); q += __shfl_down(q, o); }
    __shared__ float red[8];
    if (lane == 0) { red[wid] = s; red[4 + wid] = q; }
    __syncthreads();
    if (threadIdx.x == 0) {
        s = red[0] + red[1] + red[2] + red[3];
        q = red[4] + red[5] + red[6] + red[7];
        atomicAdd(&gsum[c], s);
        atomicAdd(&gsq[c], q);
    }
}

// ---------------- finalize BN: scale/shift from sums ----------------
__global__ void finalize_k(const float* __restrict__ gsum, const float* __restrict__ gsq,
                           const float* __restrict__ gamma, const float* __restrict__ beta,
                           float* __restrict__ sc, float* __restrict__ sh,
                           int C, float invcnt)
{
    int c = threadIdx.x;
    if (c >= C) return;
    float m   = gsum[c] * invcnt;
    float var = fmaf(gsq[c], invcnt, -m * m);
    float is  = gamma[c] * rsqrtf(var + EPSV);
    sc[c] = is;
    sh[c] = fmaf(-m, is, beta[c]);
}

// ---------------- final: BN+ReLU + global average pool ----------------
template<int HW>
__global__ __launch_bounds__(256) void avgpool_k(
    const float* __restrict__ t, const float* __restrict__ sc, const float* __restrict__ sh,
    float* __restrict__ out, int C)
{
    int nc = blockIdx.x;
    int c = nc % C;
    float scv = sc[c], shv = sh[c];
    const float* pl = t + nc * HW;
    float s = 0.f;
    for (int p = threadIdx.x; p < HW; p += 256)
        s += relu(fmaf(pl[p], scv, shv));
    int lane = threadIdx.x & 63, wid = threadIdx.x >> 6;
#pragma unroll
    for (int o = 32; o; o >>= 1) s += __shfl_down(s, o);
    __shared__ float red[4];
    if (lane == 0) red[wid] = s;
    __syncthreads();
    if (threadIdx.x == 0) out[nc] = (red[0] + red[1] + red[2] + red[3]) * (1.f / HW);
}

extern "C" void kernel_launch(void* const* d_in, const int* in_sizes, int n_in,
                              void* d_out, int out_size, void* d_ws, size_t ws_size,
                              hipStream_t stream)
{
    const float* x = (const float*)d_in[0];
    // per-block params: dw_w, dw_b, g1, be1, pw_w, pw_b, g2, be2
    const float* P[3][8];
    for (int b = 0; b < 3; b++)
        for (int j = 0; j < 8; j++)
            P[b][j] = (const float*)d_in[1 + b * 8 + j];

    float* ws = (float*)d_ws;
    // stats region: stage i in [0,6): sum = stats + i*256, sq = +128
    float* stats = ws;
    // scale/shift region: stage i: sc = scsh + i*256, sh = +128
    float* scsh = ws + 6 * 256;
    float* A = ws + 4096;            // 12,845,056 floats max
    float* B = A + 12845056;         // 25,690,112 floats max

    float* out = (float*)d_out;

    // zero the sum/sumsq accumulators (6 stages x 256 floats)
    hipMemsetAsync(stats, 0, 6 * 256 * sizeof(float), stream);

#define SUM(i) (stats + (i) * 256)
#define SQ(i)  (stats + (i) * 256 + 128)
#define SC(i)  (scsh + (i) * 256)
#define SH(i)  (scsh + (i) * 256 + 128)

    const int N = 32;
    const float inv1 = 1.f / (32.f * 12544.f);  // 401408
    const float inv2 = 1.f / (32.f * 3136.f);   // 100352

    // ---- block 0: 32 -> 64, stride 1, 112x112 ----
    dwconv_k<1, 112, 112, false><<<50176, 256, 0, stream>>>(
        x, A, P[0][0], P[0][1], nullptr, nullptr, N, 32);
    stats_k<<<dim3(32, 64), 256, 0, stream>>>(A, SUM(0), SQ(0), 32, 12544, N, 64);
    finalize_k<<<1, 128, 0, stream>>>(SUM(0), SQ(0), P[0][2], P[0][3], SC(0), SH(0), 32, inv1);

    pwconv_k<32, 64, 12544><<<1568, 256, 0, stream>>>(
        A, B, P[0][4], P[0][5], SC(0), SH(0), N);
    stats_k<<<dim3(64, 32), 256, 0, stream>>>(B, SUM(1), SQ(1), 64, 12544, N, 32);
    finalize_k<<<1, 128, 0, stream>>>(SUM(1), SQ(1), P[0][6], P[0][7], SC(1), SH(1), 64, inv1);

    // ---- block 1: 64 -> 128, stride 2, 112 -> 56 ----
    dwconv_k<2, 112, 56, true><<<25088, 256, 0, stream>>>(
        B, A, P[1][0], P[1][1], SC(1), SH(1), N, 64);
    stats_k<<<dim3(64, 32), 256, 0, stream>>>(A, SUM(2), SQ(2), 64, 3136, N, 32);
    finalize_k<<<1, 128, 0, stream>>>(SUM(2), SQ(2), P[1][2], P[1][3], SC(2), SH(2), 64, inv2);

    pwconv_k<64, 128, 3136><<<392, 256, 0, stream>>>(
        A, B, P[1][4], P[1][5], SC(2), SH(2), N);
    stats_k<<<dim3(128, 16), 256, 0, stream>>>(B, SUM(3), SQ(3), 128, 3136, N, 16);
    finalize_k<<<1, 128, 0, stream>>>(SUM(3), SQ(3), P[1][6], P[1][7], SC(3), SH(3), 128, inv2);

    // ---- block 2: 128 -> 128, stride 1, 56x56 ----
    dwconv_k<1, 56, 56, true><<<50176, 256, 0, stream>>>(
        B, A, P[2][0], P[2][1], SC(3), SH(3), N, 128);
    stats_k<<<dim3(128, 16), 256, 0, stream>>>(A, SUM(4), SQ(4), 128, 3136, N, 16);
    finalize_k<<<1, 128, 0, stream>>>(SUM(4), SQ(4), P[2][2], P[2][3], SC(4), SH(4), 128, inv2);

    pwconv_k<128, 128, 3136><<<392, 256, 0, stream>>>(
        A, B, P[2][4], P[2][5], SC(4), SH(4), N);
    stats_k<<<dim3(128, 16), 256, 0, stream>>>(B, SUM(5), SQ(5), 128, 3136, N, 16);
    finalize_k<<<1, 128, 0, stream>>>(SUM(5), SQ(5), P[2][6], P[2][7], SC(5), SH(5), 128, inv2);

    // ---- final BN+ReLU + global average pool ----
    avgpool_k<3136><<<4096, 256, 0, stream>>>(B, SC(5), SH(5), out, 128);

#undef SUM
#undef SQ
#undef SC
#undef SH
}

// Round 2
// 566.580 us; speedup vs baseline: 1.4710x; 1.4710x over previous
//
#include <hip/hip_runtime.h>

#define EPSV 1e-5f
#define NBINS 64

__device__ __forceinline__ float relu(float x) { return fmaxf(x, 0.f); }

// ---------------- depthwise 3x3, pad 1, fused per-channel stats ----------------
// If BNIN: input element x -> relu(x*sc[c] + sh[c]) before convolving.
// Grid is an exact multiple of 256 and OHW*OHW % 64 == 0, so every wave is
// fully active and covers a single channel -> wave shfl reduction is safe.
template<int S, int IHW, int OHW, bool BNIN>
__global__ __launch_bounds__(256) void dwfused_k(
    const float* __restrict__ in, float* __restrict__ out,
    const float* __restrict__ w9, const float* __restrict__ bias,
    const float* __restrict__ sc, const float* __restrict__ sh,
    float* __restrict__ bsum, float* __restrict__ bsq,
    int N, int C)
{
    const int OP = OHW * OHW;
    int idx = blockIdx.x * 256 + threadIdx.x;
    int ow = idx % OHW;
    int oh = (idx / OHW) % OHW;
    int c  = (idx / OP) % C;
    const float* ip = in + (size_t)(idx / OP) * (IHW * IHW);
    float scv = 1.f, shv = 0.f;
    if (BNIN) { scv = sc[c]; shv = sh[c]; }
    float acc = bias[c];
#pragma unroll
    for (int kh = 0; kh < 3; kh++) {
        int ih = oh * S + kh - 1;
        if ((unsigned)ih >= (unsigned)IHW) continue;
#pragma unroll
        for (int kw = 0; kw < 3; kw++) {
            int iw = ow * S + kw - 1;
            if ((unsigned)iw >= (unsigned)IHW) continue;
            float x = ip[ih * IHW + iw];
            if (BNIN) x = relu(fmaf(x, scv, shv));
            acc = fmaf(w9[c * 9 + kh * 3 + kw], x, acc);
        }
    }
    out[idx] = acc;
    // fused stats: reduce over the 64-lane wave (single channel), binned atomics
    float s = acc, q = acc * acc;
#pragma unroll
    for (int m = 32; m >= 1; m >>= 1) {
        s += __shfl_xor(s, m);
        q += __shfl_xor(q, m);
    }
    if ((threadIdx.x & 63) == 0) {
        unsigned bin = blockIdx.x & (NBINS - 1);
        atomicAdd(&bsum[bin * C + c], s);
        atomicAdd(&bsq [bin * C + c], q);
    }
}

// ---------------- pointwise 1x1 conv, register-tiled, fused stats ----------------
// 256 threads = PGN pixel-groups x CGN cout-groups. Each thread: 4 pixels x 8 couts.
// Weights staged once into LDS transposed [ci][co]; input BN+ReLU applied on load.
// PIXTILE = 4*PGN must divide HW.
template<int CIN, int COUT, int PGN, int CGN>
__global__ __launch_bounds__(256) void pwfused_k(
    const float* __restrict__ in, float* __restrict__ out,
    const float* __restrict__ w, const float* __restrict__ bias,
    const float* __restrict__ sc, const float* __restrict__ sh,
    float* __restrict__ bsum, float* __restrict__ bsq,
    int HW)
{
    static_assert(PGN * CGN == 256, "");
    static_assert(CGN * 8 == COUT, "");
    constexpr int PIXTILE = 4 * PGN;

    __shared__ float wls[CIN][COUT];   // transposed weights
    __shared__ float scs[CIN], shs[CIN];
    for (int i = threadIdx.x; i < CIN * COUT; i += 256) {
        int co = i / CIN, ci = i % CIN;
        wls[ci][co] = w[i];
    }
    if (threadIdx.x < CIN) {
        scs[threadIdx.x] = sc[threadIdx.x];
        shs[threadIdx.x] = sh[threadIdx.x];
    }
    __syncthreads();

    const int tid = threadIdx.x;
    const int pg = tid % PGN;
    const int cg = tid / PGN;
    const size_t pixbase = (size_t)blockIdx.x * PIXTILE + pg * 4;
    const int n = (int)(pixbase / HW);
    const int p = (int)(pixbase % HW);
    const float* ip = in + (size_t)n * CIN * HW + p;
    float* op = out + (size_t)n * COUT * HW + p;

    float acc[8][4];
#pragma unroll
    for (int j = 0; j < 8; j++)
#pragma unroll
        for (int q = 0; q < 4; q++) acc[j][q] = 0.f;

    for (int ci = 0; ci < CIN; ci++) {
        float4 xv = *reinterpret_cast<const float4*>(ip + (size_t)ci * HW);
        float scv = scs[ci], shv = shs[ci];
        float x0 = relu(fmaf(xv.x, scv, shv));
        float x1 = relu(fmaf(xv.y, scv, shv));
        float x2 = relu(fmaf(xv.z, scv, shv));
        float x3 = relu(fmaf(xv.w, scv, shv));
        const float4* wp = reinterpret_cast<const float4*>(&wls[ci][cg * 8]);
        float4 wa = wp[0], wb = wp[1];
        float wj[8] = {wa.x, wa.y, wa.z, wa.w, wb.x, wb.y, wb.z, wb.w};
#pragma unroll
        for (int j = 0; j < 8; j++) {
            acc[j][0] = fmaf(wj[j], x0, acc[j][0]);
            acc[j][1] = fmaf(wj[j], x1, acc[j][1]);
            acc[j][2] = fmaf(wj[j], x2, acc[j][2]);
            acc[j][3] = fmaf(wj[j], x3, acc[j][3]);
        }
    }

    const unsigned bin = blockIdx.x & (NBINS - 1);
#pragma unroll
    for (int j = 0; j < 8; j++) {
        int co = cg * 8 + j;
        float b = bias[co];
        float v0 = acc[j][0] + b, v1 = acc[j][1] + b;
        float v2 = acc[j][2] + b, v3 = acc[j][3] + b;
        float4 ov = {v0, v1, v2, v3};
        *reinterpret_cast<float4*>(op + (size_t)co * HW) = ov;
        float s = (v0 + v1) + (v2 + v3);
        float q = fmaf(v0, v0, fmaf(v1, v1, fmaf(v2, v2, v3 * v3)));
#pragma unroll
        for (int m = PGN / 2; m >= 1; m >>= 1) {
            s += __shfl_xor(s, m);
            q += __shfl_xor(q, m);
        }
        if (pg == 0) {
            atomicAdd(&bsum[bin * COUT + co], s);
            atomicAdd(&bsq [bin * COUT + co], q);
        }
    }
}

// ---------------- finalize BN: scale/shift from binned sums ----------------
__global__ void finalize_k(const float* __restrict__ bsum, const float* __restrict__ bsq,
                           const float* __restrict__ gamma, const float* __restrict__ beta,
                           float* __restrict__ sc, float* __restrict__ sh,
                           int C, float invcnt)
{
    int c = threadIdx.x;
    if (c >= C) return;
    float s = 0.f, q = 0.f;
    for (int b = 0; b < NBINS; b++) {
        s += bsum[b * C + c];
        q += bsq [b * C + c];
    }
    float m   = s * invcnt;
    float var = fmaf(q, invcnt, -m * m);
    float is  = gamma[c] * rsqrtf(var + EPSV);
    sc[c] = is;
    sh[c] = fmaf(-m, is, beta[c]);
}

// ---------------- final: BN+ReLU + global average pool ----------------
template<int HW>
__global__ __launch_bounds__(256) void avgpool_k(
    const float* __restrict__ t, const float* __restrict__ sc, const float* __restrict__ sh,
    float* __restrict__ out, int C)
{
    int nc = blockIdx.x;
    int c = nc % C;
    float scv = sc[c], shv = sh[c];
    const float* pl = t + (size_t)nc * HW;
    float s = 0.f;
    for (int p = threadIdx.x * 4; p < HW; p += 1024) {
        float4 v = *reinterpret_cast<const float4*>(pl + p);
        s += relu(fmaf(v.x, scv, shv)) + relu(fmaf(v.y, scv, shv))
           + relu(fmaf(v.z, scv, shv)) + relu(fmaf(v.w, scv, shv));
    }
    int lane = threadIdx.x & 63, wid = threadIdx.x >> 6;
#pragma unroll
    for (int o = 32; o; o >>= 1) s += __shfl_down(s, o);
    __shared__ float red[4];
    if (lane == 0) red[wid] = s;
    __syncthreads();
    if (threadIdx.x == 0) out[nc] = (red[0] + red[1] + red[2] + red[3]) * (1.f / HW);
}

extern "C" void kernel_launch(void* const* d_in, const int* in_sizes, int n_in,
                              void* d_out, int out_size, void* d_ws, size_t ws_size,
                              hipStream_t stream)
{
    const float* x = (const float*)d_in[0];
    // per-block params: dw_w, dw_b, g1, be1, pw_w, pw_b, g2, be2
    const float* P[3][8];
    for (int b = 0; b < 3; b++)
        for (int j = 0; j < 8; j++)
            P[b][j] = (const float*)d_in[1 + b * 8 + j];

    float* ws = (float*)d_ws;
    // binned stats: stage i: bsum = stats + i*16384, bsq = +8192 (NBINS=64 x 128)
    float* stats = ws;
    // scale/shift: stage i: sc = scsh + i*256, sh = +128
    float* scsh = ws + 6 * 16384;
    float* A = ws + 6 * 16384 + 1536;   // up to 12,845,056 floats
    float* B = A + 12845056;            // up to 25,690,112 floats

    float* out = (float*)d_out;

    hipMemsetAsync(stats, 0, 6 * 16384 * sizeof(float), stream);

#define BSUM(i) (stats + (i) * 16384)
#define BSQ(i)  (stats + (i) * 16384 + 8192)
#define SC(i)   (scsh + (i) * 256)
#define SH(i)   (scsh + (i) * 256 + 128)

    const int N = 32;
    const float inv1 = 1.f / (32.f * 12544.f);
    const float inv2 = 1.f / (32.f * 3136.f);

    // ---- block 0: 32 -> 64, stride 1, 112x112 ----
    dwfused_k<1, 112, 112, false><<<50176, 256, 0, stream>>>(
        x, A, P[0][0], P[0][1], nullptr, nullptr, BSUM(0), BSQ(0), N, 32);
    finalize_k<<<1, 128, 0, stream>>>(BSUM(0), BSQ(0), P[0][2], P[0][3], SC(0), SH(0), 32, inv1);

    pwfused_k<32, 64, 32, 8><<<3136, 256, 0, stream>>>(
        A, B, P[0][4], P[0][5], SC(0), SH(0), BSUM(1), BSQ(1), 12544);
    finalize_k<<<1, 128, 0, stream>>>(BSUM(1), BSQ(1), P[0][6], P[0][7], SC(1), SH(1), 64, inv1);

    // ---- block 1: 64 -> 128, stride 2, 112 -> 56 ----
    dwfused_k<2, 112, 56, true><<<25088, 256, 0, stream>>>(
        B, A, P[1][0], P[1][1], SC(1), SH(1), BSUM(2), BSQ(2), N, 64);
    finalize_k<<<1, 128, 0, stream>>>(BSUM(2), BSQ(2), P[1][2], P[1][3], SC(2), SH(2), 64, inv2);

    pwfused_k<64, 128, 16, 16><<<1568, 256, 0, stream>>>(
        A, B, P[1][4], P[1][5], SC(2), SH(2), BSUM(3), BSQ(3), 3136);
    finalize_k<<<1, 128, 0, stream>>>(BSUM(3), BSQ(3), P[1][6], P[1][7], SC(3), SH(3), 128, inv2);

    // ---- block 2: 128 -> 128, stride 1, 56x56 ----
    dwfused_k<1, 56, 56, true><<<50176, 256, 0, stream>>>(
        B, A, P[2][0], P[2][1], SC(3), SH(3), BSUM(4), BSQ(4), N, 128);
    finalize_k<<<1, 128, 0, stream>>>(BSUM(4), BSQ(4), P[2][2], P[2][3], SC(4), SH(4), 128, inv2);

    pwfused_k<128, 128, 16, 16><<<1568, 256, 0, stream>>>(
        A, B, P[2][4], P[2][5], SC(4), SH(4), BSUM(5), BSQ(5), 3136);
    finalize_k<<<1, 128, 0, stream>>>(BSUM(5), BSQ(5), P[2][6], P[2][7], SC(5), SH(5), 128, inv2);

    // ---- final BN+ReLU + global average pool ----
    avgpool_k<3136><<<4096, 256, 0, stream>>>(B, SC(5), SH(5), out, 128);

#undef BSUM
#undef BSQ
#undef SC
#undef SH
}

// Round 3
// 374.216 us; speedup vs baseline: 2.2272x; 1.5140x over previous
//
#include <hip/hip_runtime.h>

#define EPSV 1e-5f
#define NBINS 64

__device__ __forceinline__ float relu(float x) { return fmaxf(x, 0.f); }

// ---- prep: transpose the three pw weight matrices into [ci][cout] ----
__global__ void prep_k(const float* __restrict__ w0, const float* __restrict__ w1,
                       const float* __restrict__ w2, float* __restrict__ t0,
                       float* __restrict__ t1, float* __restrict__ t2)
{
    int i = blockIdx.x * 256 + threadIdx.x;          // 26624 total
    if (i < 2048)       { t0[i] = w0[(i % 64) * 32 + i / 64]; }
    else if (i < 10240) { int j = i - 2048;  t1[j] = w1[(j % 128) * 64  + j / 128]; }
    else                { int j = i - 10240; t2[j] = w2[(j % 128) * 128 + j / 128]; }
}

// ---- depthwise 3x3 pad 1, 4 px/thread, fused per-channel stats ----
template<int S, int IHW, int OHW, bool BNIN>
__global__ __launch_bounds__(256) void dwfused4_k(
    const float* __restrict__ in, float* __restrict__ out,
    const float* __restrict__ w9, const float* __restrict__ bias,
    const float* __restrict__ sc, const float* __restrict__ sh,
    float* __restrict__ bsum, float* __restrict__ bsq, int C)
{
    const int OP = OHW * OHW;
    int idx  = blockIdx.x * 256 + threadIdx.x;
    int pix4 = idx * 4;                      // 4-aligned, OHW%4==0 -> same row
    int ow = pix4 % OHW;
    int oh = (pix4 / OHW) % OHW;
    int pl = pix4 / OP;                      // n*C + c
    int c  = pl % C;
    const float* ip = in + (size_t)pl * (IHW * IHW);
    float scv = 1.f, shv = 0.f;
    if (BNIN) { scv = sc[c]; shv = sh[c]; }
    float wv[9];
#pragma unroll
    for (int k = 0; k < 9; k++) wv[k] = w9[c * 9 + k];
    float bz = bias[c];
    float a0 = bz, a1 = bz, a2 = bz, a3 = bz;
    const int icb = ow * S;                  // S=1: 4-aligned; S=2: 8-aligned

    auto T = [&](float v) { return BNIN ? relu(fmaf(v, scv, shv)) : v; };

#pragma unroll
    for (int kh = 0; kh < 3; kh++) {
        int ih = oh * S + kh - 1;
        if ((unsigned)ih >= (unsigned)IHW) continue;   // zero row: contributes 0
        const float* rp = ip + ih * IHW;
        float sq[3 * S + 3];
        float4 M = *(const float4*)(rp + icb);
        sq[1] = T(M.x); sq[2] = T(M.y); sq[3] = T(M.z); sq[4] = T(M.w);
        sq[0] = (icb > 0) ? T(rp[icb - 1]) : 0.f;      // pad AFTER activation
        if (S == 1) {
            sq[5] = (icb + 4 < IHW) ? T(rp[icb + 4]) : 0.f;
        } else {
            float4 R = *(const float4*)(rp + icb + 4); // 2ow+7 <= IHW-1 always
            sq[5] = T(R.x); sq[6] = T(R.y); sq[7] = T(R.z); sq[8] = T(R.w);
        }
        float k0 = wv[kh * 3], k1 = wv[kh * 3 + 1], k2 = wv[kh * 3 + 2];
        a0 = fmaf(k0, sq[0],     fmaf(k1, sq[1],         fmaf(k2, sq[2],         a0)));
        a1 = fmaf(k0, sq[S],     fmaf(k1, sq[S + 1],     fmaf(k2, sq[S + 2],     a1)));
        a2 = fmaf(k0, sq[2 * S], fmaf(k1, sq[2 * S + 1], fmaf(k2, sq[2 * S + 2], a2)));
        a3 = fmaf(k0, sq[3 * S], fmaf(k1, sq[3 * S + 1], fmaf(k2, sq[3 * S + 2], a3)));
    }
    float4 ov = {a0, a1, a2, a3};
    *(float4*)(out + pix4) = ov;

    // stats over 16-lane group (64 consecutive px; 64 divides all plane sizes)
    float s = (a0 + a1) + (a2 + a3);
    float q = fmaf(a0, a0, fmaf(a1, a1, fmaf(a2, a2, a3 * a3)));
#pragma unroll
    for (int m = 8; m >= 1; m >>= 1) { s += __shfl_xor(s, m); q += __shfl_xor(q, m); }
    if ((threadIdx.x & 15) == 0) {
        unsigned bin = blockIdx.x & (NBINS - 1);
        atomicAdd(&bsum[bin * C + c], s);
        atomicAdd(&bsq [bin * C + c], q);
    }
}

// ---- pointwise 1x1, register-tiled GEMM, pipelined, fused stats ----
// COB couts per block (blockIdx.y selects slice). Pre-transposed weights wT[ci][COUT].
template<int CIN, int COUT, int COB, int HW>
__global__ __launch_bounds__(256, 4) void pwfused_k(
    const float* __restrict__ in, float* __restrict__ out,
    const float* __restrict__ wT, const float* __restrict__ bias,
    const float* __restrict__ sc, const float* __restrict__ sh,
    float* __restrict__ bsum, float* __restrict__ bsq)
{
    constexpr int CGN = COB / 8;
    constexpr int PGN = 256 / CGN;
    constexpr int TILE = 4 * PGN;
    __shared__ float wls[CIN * COB];
    __shared__ float scs[CIN], shs[CIN];
    const int cos0 = blockIdx.y * COB;
    for (int i = threadIdx.x * 4; i < CIN * COB; i += 1024) {
        int ci = i / COB, co = i % COB;                 // co stays 4-aligned
        *(float4*)&wls[i] = *(const float4*)&wT[ci * COUT + cos0 + co];
    }
    if (threadIdx.x < CIN) {
        scs[threadIdx.x] = sc[threadIdx.x];
        shs[threadIdx.x] = sh[threadIdx.x];
    }
    __syncthreads();

    const int tid = threadIdx.x;
    const int pg = tid % PGN;
    const int cg = tid / PGN;
    const size_t pixbase = (size_t)blockIdx.x * TILE + pg * 4;
    const int n = (int)(pixbase / HW);                  // HW%4==0 -> 4px same n
    const int p = (int)(pixbase % HW);
    const float* ip = in + ((size_t)n * CIN) * HW + p;
    float* op = out + ((size_t)n * COUT) * HW + p;

    float acc[8][4];
#pragma unroll
    for (int j = 0; j < 8; j++)
#pragma unroll
        for (int q = 0; q < 4; q++) acc[j][q] = 0.f;

    constexpr int ST = CIN / 4;
    float4 cur[4];
#pragma unroll
    for (int u = 0; u < 4; u++) cur[u] = *(const float4*)(ip + (size_t)u * HW);

#pragma unroll 2
    for (int t = 0; t < ST; t++) {
        float4 nxt[4];
#pragma unroll
        for (int u = 0; u < 4; u++) nxt[u] = cur[u];
        if (t + 1 < ST) {
#pragma unroll
            for (int u = 0; u < 4; u++)
                nxt[u] = *(const float4*)(ip + (size_t)((t + 1) * 4 + u) * HW);
        }
#pragma unroll
        for (int u = 0; u < 4; u++) {
            const int ci = t * 4 + u;
            float scv = scs[ci], shv = shs[ci];
            float x0 = relu(fmaf(cur[u].x, scv, shv));
            float x1 = relu(fmaf(cur[u].y, scv, shv));
            float x2 = relu(fmaf(cur[u].z, scv, shv));
            float x3 = relu(fmaf(cur[u].w, scv, shv));
            const float4* wp = (const float4*)&wls[ci * COB + cg * 8];
            float4 wa = wp[0], wb = wp[1];
            float wj[8] = {wa.x, wa.y, wa.z, wa.w, wb.x, wb.y, wb.z, wb.w};
#pragma unroll
            for (int j = 0; j < 8; j++) {
                acc[j][0] = fmaf(wj[j], x0, acc[j][0]);
                acc[j][1] = fmaf(wj[j], x1, acc[j][1]);
                acc[j][2] = fmaf(wj[j], x2, acc[j][2]);
                acc[j][3] = fmaf(wj[j], x3, acc[j][3]);
            }
        }
#pragma unroll
        for (int u = 0; u < 4; u++) cur[u] = nxt[u];
    }

    const unsigned bin = blockIdx.x & (NBINS - 1);
#pragma unroll
    for (int j = 0; j < 8; j++) {
        int co = cos0 + cg * 8 + j;
        float bz = bias[co];
        float v0 = acc[j][0] + bz, v1 = acc[j][1] + bz;
        float v2 = acc[j][2] + bz, v3 = acc[j][3] + bz;
        float4 ov = {v0, v1, v2, v3};
        *(float4*)(op + (size_t)co * HW) = ov;
        float s = (v0 + v1) + (v2 + v3);
        float q = fmaf(v0, v0, fmaf(v1, v1, fmaf(v2, v2, v3 * v3)));
#pragma unroll
        for (int m = PGN / 2; m >= 1; m >>= 1) { s += __shfl_xor(s, m); q += __shfl_xor(q, m); }
        if (pg == 0) {
            atomicAdd(&bsum[bin * COUT + co], s);
            atomicAdd(&bsq [bin * COUT + co], q);
        }
    }
}

// ---- finalize BN: scale/shift from binned sums ----
__global__ void finalize_k(const float* __restrict__ bsum, const float* __restrict__ bsq,
                           const float* __restrict__ gamma, const float* __restrict__ beta,
                           float* __restrict__ sc, float* __restrict__ sh,
                           int C, float invcnt)
{
    int c = threadIdx.x;
    if (c >= C) return;
    float s = 0.f, q = 0.f;
    for (int b = 0; b < NBINS; b++) {
        s += bsum[b * C + c];
        q += bsq [b * C + c];
    }
    float m   = s * invcnt;
    float var = fmaf(q, invcnt, -m * m);
    float is  = gamma[c] * rsqrtf(var + EPSV);
    sc[c] = is;
    sh[c] = fmaf(-m, is, beta[c]);
}

// ---- final: BN+ReLU + global average pool ----
template<int HW>
__global__ __launch_bounds__(256) void avgpool_k(
    const float* __restrict__ t, const float* __restrict__ sc, const float* __restrict__ sh,
    float* __restrict__ out, int C)
{
    int nc = blockIdx.x;
    int c = nc % C;
    float scv = sc[c], shv = sh[c];
    const float* pl = t + (size_t)nc * HW;
    float s = 0.f;
    for (int p = threadIdx.x * 4; p < HW; p += 1024) {
        float4 v = *reinterpret_cast<const float4*>(pl + p);
        s += relu(fmaf(v.x, scv, shv)) + relu(fmaf(v.y, scv, shv))
           + relu(fmaf(v.z, scv, shv)) + relu(fmaf(v.w, scv, shv));
    }
    int lane = threadIdx.x & 63, wid = threadIdx.x >> 6;
#pragma unroll
    for (int o = 32; o; o >>= 1) s += __shfl_down(s, o);
    __shared__ float red[4];
    if (lane == 0) red[wid] = s;
    __syncthreads();
    if (threadIdx.x == 0) out[nc] = (red[0] + red[1] + red[2] + red[3]) * (1.f / HW);
}

extern "C" void kernel_launch(void* const* d_in, const int* in_sizes, int n_in,
                              void* d_out, int out_size, void* d_ws, size_t ws_size,
                              hipStream_t stream)
{
    const float* x = (const float*)d_in[0];
    const float* P[3][8];
    for (int b = 0; b < 3; b++)
        for (int j = 0; j < 8; j++)
            P[b][j] = (const float*)d_in[1 + b * 8 + j];

    float* ws = (float*)d_ws;
    float* stats = ws;                       // 6 * 16384
    float* scsh  = ws + 6 * 16384;           // 1536
    float* wT0   = scsh + 1536;              // 2048
    float* wT1   = wT0 + 2048;               // 8192
    float* wT2   = wT1 + 8192;               // 16384
    float* A     = wT2 + 16384;              // up to 12,845,056 floats
    float* B     = A + 12845056;             // up to 25,690,112 floats

    float* out = (float*)d_out;

    hipMemsetAsync(stats, 0, 6 * 16384 * sizeof(float), stream);
    prep_k<<<104, 256, 0, stream>>>(P[0][4], P[1][4], P[2][4], wT0, wT1, wT2);

#define BSUM(i) (stats + (i) * 16384)
#define BSQ(i)  (stats + (i) * 16384 + 8192)
#define SC(i)   (scsh + (i) * 256)
#define SH(i)   (scsh + (i) * 256 + 128)

    const float inv1 = 1.f / (32.f * 12544.f);
    const float inv2 = 1.f / (32.f * 3136.f);

    // ---- block 0: 32 -> 64, stride 1, 112x112 ----
    dwfused4_k<1, 112, 112, false><<<12544, 256, 0, stream>>>(
        x, A, P[0][0], P[0][1], nullptr, nullptr, BSUM(0), BSQ(0), 32);
    finalize_k<<<1, 128, 0, stream>>>(BSUM(0), BSQ(0), P[0][2], P[0][3], SC(0), SH(0), 32, inv1);

    pwfused_k<32, 64, 64, 12544><<<dim3(3136, 1), 256, 0, stream>>>(
        A, B, wT0, P[0][5], SC(0), SH(0), BSUM(1), BSQ(1));
    finalize_k<<<1, 128, 0, stream>>>(BSUM(1), BSQ(1), P[0][6], P[0][7], SC(1), SH(1), 64, inv1);

    // ---- block 1: 64 -> 128, stride 2, 112 -> 56 ----
    dwfused4_k<2, 112, 56, true><<<6272, 256, 0, stream>>>(
        B, A, P[1][0], P[1][1], SC(1), SH(1), BSUM(2), BSQ(2), 64);
    finalize_k<<<1, 128, 0, stream>>>(BSUM(2), BSQ(2), P[1][2], P[1][3], SC(2), SH(2), 64, inv2);

    pwfused_k<64, 128, 128, 3136><<<dim3(1568, 1), 256, 0, stream>>>(
        A, B, wT1, P[1][5], SC(2), SH(2), BSUM(3), BSQ(3));
    finalize_k<<<1, 128, 0, stream>>>(BSUM(3), BSQ(3), P[1][6], P[1][7], SC(3), SH(3), 128, inv2);

    // ---- block 2: 128 -> 128, stride 1, 56x56 ----
    dwfused4_k<1, 56, 56, true><<<12544, 256, 0, stream>>>(
        B, A, P[2][0], P[2][1], SC(3), SH(3), BSUM(4), BSQ(4), 128);
    finalize_k<<<1, 128, 0, stream>>>(BSUM(4), BSQ(4), P[2][2], P[2][3], SC(4), SH(4), 128, inv2);

    pwfused_k<128, 128, 64, 3136><<<dim3(784, 2), 256, 0, stream>>>(
        A, B, wT2, P[2][5], SC(4), SH(4), BSUM(5), BSQ(5));
    finalize_k<<<1, 128, 0, stream>>>(BSUM(5), BSQ(5), P[2][6], P[2][7], SC(5), SH(5), 128, inv2);

    // ---- final BN+ReLU + global average pool ----
    avgpool_k<3136><<<4096, 256, 0, stream>>>(B, SC(5), SH(5), out, 128);

#undef BSUM
#undef BSQ
#undef SC
#undef SH
}

// Round 4
// 323.132 us; speedup vs baseline: 2.5793x; 1.1581x over previous
//
#include <hip/hip_runtime.h>

#define EPSV 1e-5f
#define NBINS 64

typedef unsigned short u16;
typedef unsigned int u32;
typedef __attribute__((ext_vector_type(8))) short short8;
typedef __attribute__((ext_vector_type(4))) float f32x4;

__device__ __forceinline__ float relu(float x) { return fmaxf(x, 0.f); }

// fp32 -> bf16 round-to-nearest-even (finite values only)
__device__ __forceinline__ u16 f2bf(float f) {
    u32 u = __builtin_bit_cast(u32, f);
    u32 r = (u + 0x7fffu + ((u >> 16) & 1u)) >> 16;
    return (u16)r;
}

// ---- prep: swizzle the three pw weight matrices into A-fragment order ----
// A-frag for mfma_f32_16x16x32_bf16: lane l holds A[m=l&15][k=8*(l>>4)+i], i=0..7.
// Word w = (ks*NT + t)*64 + lane; value = W[16t + (l&15)][32ks + 8(l>>4) + i].
template<int CIN, int COUT>
__device__ __forceinline__ void prep_one(const float* __restrict__ w,
                                         u16* __restrict__ dst, int widx) {
    const int NT = COUT / 16;
    int lane = widx & 63;
    int t  = (widx >> 6) % NT;
    int ks = (widx >> 6) / NT;
    int co  = t * 16 + (lane & 15);
    int ci0 = ks * 32 + (lane >> 4) * 8;
#pragma unroll
    for (int i = 0; i < 8; i++)
        dst[(size_t)widx * 8 + i] = f2bf(w[co * CIN + ci0 + i]);
}

__global__ void prep_k(const float* __restrict__ w0, const float* __restrict__ w1,
                       const float* __restrict__ w2, u16* __restrict__ s0,
                       u16* __restrict__ s1, u16* __restrict__ s2) {
    int i = blockIdx.x * 256 + threadIdx.x;          // 3328 words total
    if (i < 256)       prep_one<32, 64>  (w0, s0, i);
    else if (i < 1280) prep_one<64, 128> (w1, s1, i - 256);
    else if (i < 3328) prep_one<128, 128>(w2, s2, i - 1280);
}

// ---- depthwise 3x3 pad 1, 4 px/thread, fused per-channel stats (fp32) ----
template<int S, int IHW, int OHW, bool BNIN>
__global__ __launch_bounds__(256) void dwfused4_k(
    const float* __restrict__ in, float* __restrict__ out,
    const float* __restrict__ w9, const float* __restrict__ bias,
    const float* __restrict__ sc, const float* __restrict__ sh,
    float* __restrict__ bsum, float* __restrict__ bsq, int C)
{
    const int OP = OHW * OHW;
    int idx  = blockIdx.x * 256 + threadIdx.x;
    int pix4 = idx * 4;
    int ow = pix4 % OHW;
    int oh = (pix4 / OHW) % OHW;
    int pl = pix4 / OP;
    int c  = pl % C;
    const float* ip = in + (size_t)pl * (IHW * IHW);
    float scv = 1.f, shv = 0.f;
    if (BNIN) { scv = sc[c]; shv = sh[c]; }
    float wv[9];
#pragma unroll
    for (int k = 0; k < 9; k++) wv[k] = w9[c * 9 + k];
    float bz = bias[c];
    float a0 = bz, a1 = bz, a2 = bz, a3 = bz;
    const int icb = ow * S;

    auto T = [&](float v) { return BNIN ? relu(fmaf(v, scv, shv)) : v; };

#pragma unroll
    for (int kh = 0; kh < 3; kh++) {
        int ih = oh * S + kh - 1;
        if ((unsigned)ih >= (unsigned)IHW) continue;
        const float* rp = ip + ih * IHW;
        float sq[3 * S + 3];
        float4 M = *(const float4*)(rp + icb);
        sq[1] = T(M.x); sq[2] = T(M.y); sq[3] = T(M.z); sq[4] = T(M.w);
        sq[0] = (icb > 0) ? T(rp[icb - 1]) : 0.f;
        if (S == 1) {
            sq[5] = (icb + 4 < IHW) ? T(rp[icb + 4]) : 0.f;
        } else {
            float4 R = *(const float4*)(rp + icb + 4);
            sq[5] = T(R.x); sq[6] = T(R.y); sq[7] = T(R.z); sq[8] = T(R.w);
        }
        float k0 = wv[kh * 3], k1 = wv[kh * 3 + 1], k2 = wv[kh * 3 + 2];
        a0 = fmaf(k0, sq[0],     fmaf(k1, sq[1],         fmaf(k2, sq[2],         a0)));
        a1 = fmaf(k0, sq[S],     fmaf(k1, sq[S + 1],     fmaf(k2, sq[S + 2],     a1)));
        a2 = fmaf(k0, sq[2 * S], fmaf(k1, sq[2 * S + 1], fmaf(k2, sq[2 * S + 2], a2)));
        a3 = fmaf(k0, sq[3 * S], fmaf(k1, sq[3 * S + 1], fmaf(k2, sq[3 * S + 2], a3)));
    }
    float4 ov = {a0, a1, a2, a3};
    *(float4*)(out + pix4) = ov;

    float s = (a0 + a1) + (a2 + a3);
    float q = fmaf(a0, a0, fmaf(a1, a1, fmaf(a2, a2, a3 * a3)));
#pragma unroll
    for (int m = 8; m >= 1; m >>= 1) { s += __shfl_xor(s, m); q += __shfl_xor(q, m); }
    if ((threadIdx.x & 15) == 0) {
        unsigned bin = blockIdx.x & (NBINS - 1);
        atomicAdd(&bsum[bin * C + c], s);
        atomicAdd(&bsq [bin * C + c], q);
    }
}

// ---- pointwise 1x1 conv via bf16 MFMA, fused BN+ReLU on load + stats ----
// Block: 256 threads = 4 waves; tile = 64 px x COUT couts. A=W (m=co), B=X (n=px).
// X staged in LDS in exact B-fragment order; W read from pre-swizzled global.
template<int CIN, int COUT, int HW>
__global__ __launch_bounds__(256, 4) void pwmfma_k(
    const float* __restrict__ in, float* __restrict__ out,
    const u16* __restrict__ wswz, const float* __restrict__ bias,
    const float* __restrict__ sc, const float* __restrict__ sh,
    float* __restrict__ bsum, float* __restrict__ bsq)
{
    constexpr int NK = CIN / 32;    // K-steps
    constexpr int NT = COUT / 16;   // co tiles
    __shared__ u16 frag[4 * NK * 512];       // [pxgrp][ks][lane][8] bf16
    __shared__ float lsum[4 * COUT];
    __shared__ float lsq [4 * COUT];

    const int tid = threadIdx.x;
    const size_t pixbase = (size_t)blockIdx.x * 64;   // HW % 64 == 0
    const int n  = (int)(pixbase / HW);
    const int p0 = (int)(pixbase % HW);
    const float* ipb = in + ((size_t)n * CIN) * HW + p0;

    // ---- stage X tile [CIN][64px]: BN+ReLU, cvt bf16, write frag-order ----
    {
        const int pxo = (tid & 15) * 4;       // 4-aligned px offset in tile
        const int pg  = pxo >> 4;
        const int ci0 = (tid >> 4) * 2;       // even ci in [0,32)
        for (int cs = 0; cs < CIN; cs += 32) {
            int ci = cs + ci0;
            float4 xa = *(const float4*)(ipb + (size_t)ci * HW + pxo);
            float4 xb = *(const float4*)(ipb + (size_t)(ci + 1) * HW + pxo);
            float sa = sc[ci],     ha = sh[ci];
            float sb = sc[ci + 1], hb = sh[ci + 1];
            float a0 = relu(fmaf(xa.x, sa, ha)), a1 = relu(fmaf(xa.y, sa, ha));
            float a2 = relu(fmaf(xa.z, sa, ha)), a3 = relu(fmaf(xa.w, sa, ha));
            float b0 = relu(fmaf(xb.x, sb, hb)), b1 = relu(fmaf(xb.y, sb, hb));
            float b2 = relu(fmaf(xb.z, sb, hb)), b3 = relu(fmaf(xb.w, sb, hb));
            int ks = ci >> 5;
            int g  = (ci & 31) >> 3;
            int i0 = ci & 7;                  // even
            int bu = ((pg * NK + ks) * 64 + g * 16 + (pxo & 15)) * 8 + i0;
            *(u32*)&frag[bu]      = (u32)f2bf(a0) | ((u32)f2bf(b0) << 16);
            *(u32*)&frag[bu + 8]  = (u32)f2bf(a1) | ((u32)f2bf(b1) << 16);
            *(u32*)&frag[bu + 16] = (u32)f2bf(a2) | ((u32)f2bf(b2) << 16);
            *(u32*)&frag[bu + 24] = (u32)f2bf(a3) | ((u32)f2bf(b3) << 16);
        }
    }
    __syncthreads();

    // ---- MFMA K-loop: wave wv owns px-group wv (16 px) x all COUT ----
    const int wv   = tid >> 6;
    const int lane = tid & 63;
    f32x4 acc[NT];
#pragma unroll
    for (int t = 0; t < NT; t++) acc[t] = (f32x4){0.f, 0.f, 0.f, 0.f};

    const short8* wp = (const short8*)wswz;
#pragma unroll
    for (int ks = 0; ks < NK; ks++) {
        short8 bf = *(const short8*)&frag[((wv * NK + ks) * 64 + lane) * 8];
#pragma unroll
        for (int t = 0; t < NT; t++) {
            short8 af = wp[(ks * NT + t) * 64 + lane];
            acc[t] = __builtin_amdgcn_mfma_f32_16x16x32_bf16(af, bf, acc[t], 0, 0, 0);
        }
    }

    // ---- epilogue: bias, store, fused stats ----
    const int g   = lane >> 4;
    const int col = lane & 15;
    const int p   = p0 + wv * 16 + col;
    const unsigned bin = blockIdx.x & (NBINS - 1);
#pragma unroll
    for (int t = 0; t < NT; t++) {
#pragma unroll
        for (int i = 0; i < 4; i++) {
            int co = t * 16 + g * 4 + i;
            float v = acc[t][i] + bias[co];
            out[((size_t)n * COUT + co) * HW + p] = v;
            float s = v, q = v * v;
            s += __shfl_xor(s, 1); q += __shfl_xor(q, 1);
            s += __shfl_xor(s, 2); q += __shfl_xor(q, 2);
            s += __shfl_xor(s, 4); q += __shfl_xor(q, 4);
            s += __shfl_xor(s, 8); q += __shfl_xor(q, 8);
            if (col == 0) { lsum[wv * COUT + co] = s; lsq[wv * COUT + co] = q; }
        }
    }
    __syncthreads();
    if (tid < COUT) {
        float s = lsum[tid] + lsum[COUT + tid] + lsum[2 * COUT + tid] + lsum[3 * COUT + tid];
        float q = lsq[tid]  + lsq[COUT + tid]  + lsq[2 * COUT + tid]  + lsq[3 * COUT + tid];
        atomicAdd(&bsum[bin * COUT + tid], s);
        atomicAdd(&bsq [bin * COUT + tid], q);
    }
}

// ---- finalize BN: scale/shift from binned sums ----
__global__ void finalize_k(const float* __restrict__ bsum, const float* __restrict__ bsq,
                           const float* __restrict__ gamma, const float* __restrict__ beta,
                           float* __restrict__ sc, float* __restrict__ sh,
                           int C, float invcnt)
{
    int c = threadIdx.x;
    if (c >= C) return;
    float s = 0.f, q = 0.f;
    for (int b = 0; b < NBINS; b++) {
        s += bsum[b * C + c];
        q += bsq [b * C + c];
    }
    float m   = s * invcnt;
    float var = fmaf(q, invcnt, -m * m);
    float is  = gamma[c] * rsqrtf(var + EPSV);
    sc[c] = is;
    sh[c] = fmaf(-m, is, beta[c]);
}

// ---- final: BN+ReLU + global average pool ----
template<int HW>
__global__ __launch_bounds__(256) void avgpool_k(
    const float* __restrict__ t, const float* __restrict__ sc, const float* __restrict__ sh,
    float* __restrict__ out, int C)
{
    int nc = blockIdx.x;
    int c = nc % C;
    float scv = sc[c], shv = sh[c];
    const float* pl = t + (size_t)nc * HW;
    float s = 0.f;
    for (int p = threadIdx.x * 4; p < HW; p += 1024) {
        float4 v = *reinterpret_cast<const float4*>(pl + p);
        s += relu(fmaf(v.x, scv, shv)) + relu(fmaf(v.y, scv, shv))
           + relu(fmaf(v.z, scv, shv)) + relu(fmaf(v.w, scv, shv));
    }
    int lane = threadIdx.x & 63, wid = threadIdx.x >> 6;
#pragma unroll
    for (int o = 32; o; o >>= 1) s += __shfl_down(s, o);
    __shared__ float red[4];
    if (lane == 0) red[wid] = s;
    __syncthreads();
    if (threadIdx.x == 0) out[nc] = (red[0] + red[1] + red[2] + red[3]) * (1.f / HW);
}

extern "C" void kernel_launch(void* const* d_in, const int* in_sizes, int n_in,
                              void* d_out, int out_size, void* d_ws, size_t ws_size,
                              hipStream_t stream)
{
    const float* x = (const float*)d_in[0];
    const float* P[3][8];
    for (int b = 0; b < 3; b++)
        for (int j = 0; j < 8; j++)
            P[b][j] = (const float*)d_in[1 + b * 8 + j];

    float* ws = (float*)d_ws;
    float* stats = ws;                       // 6 * 16384 f32
    float* scsh  = ws + 6 * 16384;           // 1536 f32
    u16*  wswz0  = (u16*)(scsh + 1536);      // 2048 u16 (16B aligned)
    u16*  wswz1  = wswz0 + 2048;             // 8192 u16
    u16*  wswz2  = wswz1 + 8192;             // 16384 u16
    float* A     = (float*)(wswz2 + 16384);  // up to 12,845,056 f32
    float* B     = A + 12845056;             // up to 25,690,112 f32

    float* out = (float*)d_out;

    hipMemsetAsync(stats, 0, 6 * 16384 * sizeof(float), stream);
    prep_k<<<13, 256, 0, stream>>>(P[0][4], P[1][4], P[2][4], wswz0, wswz1, wswz2);

#define BSUM(i) (stats + (i) * 16384)
#define BSQ(i)  (stats + (i) * 16384 + 8192)
#define SC(i)   (scsh + (i) * 256)
#define SH(i)   (scsh + (i) * 256 + 128)

    const float inv1 = 1.f / (32.f * 12544.f);
    const float inv2 = 1.f / (32.f * 3136.f);

    // ---- block 0: 32 -> 64, stride 1, 112x112 ----
    dwfused4_k<1, 112, 112, false><<<12544, 256, 0, stream>>>(
        x, A, P[0][0], P[0][1], nullptr, nullptr, BSUM(0), BSQ(0), 32);
    finalize_k<<<1, 128, 0, stream>>>(BSUM(0), BSQ(0), P[0][2], P[0][3], SC(0), SH(0), 32, inv1);

    pwmfma_k<32, 64, 12544><<<6272, 256, 0, stream>>>(
        A, B, wswz0, P[0][5], SC(0), SH(0), BSUM(1), BSQ(1));
    finalize_k<<<1, 128, 0, stream>>>(BSUM(1), BSQ(1), P[0][6], P[0][7], SC(1), SH(1), 64, inv1);

    // ---- block 1: 64 -> 128, stride 2, 112 -> 56 ----
    dwfused4_k<2, 112, 56, true><<<6272, 256, 0, stream>>>(
        B, A, P[1][0], P[1][1], SC(1), SH(1), BSUM(2), BSQ(2), 64);
    finalize_k<<<1, 128, 0, stream>>>(BSUM(2), BSQ(2), P[1][2], P[1][3], SC(2), SH(2), 64, inv2);

    pwmfma_k<64, 128, 3136><<<1568, 256, 0, stream>>>(
        A, B, wswz1, P[1][5], SC(2), SH(2), BSUM(3), BSQ(3));
    finalize_k<<<1, 128, 0, stream>>>(BSUM(3), BSQ(3), P[1][6], P[1][7], SC(3), SH(3), 128, inv2);

    // ---- block 2: 128 -> 128, stride 1, 56x56 ----
    dwfused4_k<1, 56, 56, true><<<12544, 256, 0, stream>>>(
        B, A, P[2][0], P[2][1], SC(3), SH(3), BSUM(4), BSQ(4), 128);
    finalize_k<<<1, 128, 0, stream>>>(BSUM(4), BSQ(4), P[2][2], P[2][3], SC(4), SH(4), 128, inv2);

    pwmfma_k<128, 128, 3136><<<1568, 256, 0, stream>>>(
        A, B, wswz2, P[2][5], SC(4), SH(4), BSUM(5), BSQ(5));
    finalize_k<<<1, 128, 0, stream>>>(BSUM(5), BSQ(5), P[2][6], P[2][7], SC(5), SH(5), 128, inv2);

    // ---- final BN+ReLU + global average pool ----
    avgpool_k<3136><<<4096, 256, 0, stream>>>(B, SC(5), SH(5), out, 128);

#undef BSUM
#undef BSQ
#undef SC
#undef SH
}

// Round 5
// 247.600 us; speedup vs baseline: 3.3661x; 1.3051x over previous
//
#include <hip/hip_runtime.h>

#define EPSV 1e-5f
#define NBINS 64

typedef unsigned short u16;
typedef unsigned int u32;
typedef __attribute__((ext_vector_type(4))) unsigned short ush4;
typedef __attribute__((ext_vector_type(8))) unsigned short ush8;
typedef __attribute__((ext_vector_type(8))) short short8;
typedef __attribute__((ext_vector_type(4))) float f32x4;

__device__ __forceinline__ float relu(float x) { return fmaxf(x, 0.f); }

// fp32 -> bf16 round-to-nearest-even (finite values only)
__device__ __forceinline__ u16 f2bf(float f) {
    u32 u = __builtin_bit_cast(u32, f);
    u32 r = (u + 0x7fffu + ((u >> 16) & 1u)) >> 16;
    return (u16)r;
}
__device__ __forceinline__ float bf2f(u16 v) {
    return __builtin_bit_cast(float, (u32)v << 16);
}

// ---- prep: swizzle the three pw weight matrices into A-fragment order ----
// A-frag for mfma_f32_16x16x32_bf16: lane l holds A[m=l&15][k=8*(l>>4)+i], i=0..7.
template<int CIN, int COUT>
__device__ __forceinline__ void prep_one(const float* __restrict__ w,
                                         u16* __restrict__ dst, int widx) {
    const int NT = COUT / 16;
    int lane = widx & 63;
    int t  = (widx >> 6) % NT;
    int ks = (widx >> 6) / NT;
    int co  = t * 16 + (lane & 15);
    int ci0 = ks * 32 + (lane >> 4) * 8;
#pragma unroll
    for (int i = 0; i < 8; i++)
        dst[(size_t)widx * 8 + i] = f2bf(w[co * CIN + ci0 + i]);
}

__global__ void prep_k(const float* __restrict__ w0, const float* __restrict__ w1,
                       const float* __restrict__ w2, u16* __restrict__ s0,
                       u16* __restrict__ s1, u16* __restrict__ s2) {
    int i = blockIdx.x * 256 + threadIdx.x;          // 3328 words total
    if (i < 256)       prep_one<32, 64>  (w0, s0, i);
    else if (i < 1280) prep_one<64, 128> (w1, s1, i - 256);
    else if (i < 3328) prep_one<128, 128>(w2, s2, i - 1280);
}

// ---- depthwise 3x3 pad 1: 4x4 output tile per thread, fused stats ----
// Input TIN = float (block 0) or u16/bf16. Output bf16. Stats in fp32.
// G = stats lane-group size; requires (OHW/4)^2 % G == 0 (no plane crossing).
template<int S, int IHW, int OHW, int C, bool BNIN, int G, typename TIN>
__global__ __launch_bounds__(256) void dwtile_k(
    const TIN* __restrict__ in, u16* __restrict__ out,
    const float* __restrict__ w9, const float* __restrict__ bias,
    const float* __restrict__ sc, const float* __restrict__ sh,
    float* __restrict__ bsum, float* __restrict__ bsq)
{
    constexpr bool F32 = sizeof(TIN) == 4;
    constexpr int CT = OHW / 4;            // col tiles per row
    constexpr int TPP = CT * CT;           // threads per plane
    constexpr int NR = 3 + 3 * S;          // input rows touched per tile
    constexpr int NQ = 3 + 3 * S;          // input cols touched per tile

    int t = blockIdx.x * 256 + threadIdx.x;
    int plane = t / TPP;
    int w = t % TPP;
    int rt = w / CT, ct = w % CT;
    int c = plane & (C - 1);

    const TIN* base = in + (size_t)plane * (IHW * IHW);
    float scv = 1.f, shv = 0.f;
    if (BNIN) { scv = sc[c]; shv = sh[c]; }
    float wv[9];
#pragma unroll
    for (int k = 0; k < 9; k++) wv[k] = w9[c * 9 + k];
    float bz = bias[c];

    float acc[4][4];
#pragma unroll
    for (int j = 0; j < 4; j++)
#pragma unroll
        for (int cc = 0; cc < 4; cc++) acc[j][cc] = bz;

    const int r0 = rt * 4;
    const int icb = ct * 4 * S;

    auto T = [&](float v) { return BNIN ? relu(fmaf(v, scv, shv)) : v; };

#pragma unroll
    for (int rin = 0; rin < NR; rin++) {
        int ih = r0 * S + rin - 1;
        if (ih < 0 || ih >= IHW) continue;
        const TIN* rp = base + (size_t)ih * IHW;
        float sq[NQ];
        if constexpr (S == 1) {
            float r1, r2, r3, r4;
            if constexpr (F32) {
                float4 M = *(const float4*)(rp + icb);
                r1 = M.x; r2 = M.y; r3 = M.z; r4 = M.w;
            } else {
                ush4 M = *(const ush4*)(rp + icb);
                r1 = bf2f(M[0]); r2 = bf2f(M[1]); r3 = bf2f(M[2]); r4 = bf2f(M[3]);
            }
            sq[1] = T(r1); sq[2] = T(r2); sq[3] = T(r3); sq[4] = T(r4);
            if (icb > 0) {
                float e = F32 ? (float)rp[icb - 1] : bf2f(*(const u16*)(rp + icb - 1));
                sq[0] = T(e);
            } else sq[0] = 0.f;
            if (icb + 4 < IHW) {
                float e = F32 ? (float)rp[icb + 4] : bf2f(*(const u16*)(rp + icb + 4));
                sq[5] = T(e);
            } else sq[5] = 0.f;
        } else {
            float r[8];
            if constexpr (F32) {
                float4 M = *(const float4*)(rp + icb);
                float4 R = *(const float4*)(rp + icb + 4);
                r[0] = M.x; r[1] = M.y; r[2] = M.z; r[3] = M.w;
                r[4] = R.x; r[5] = R.y; r[6] = R.z; r[7] = R.w;
            } else {
                ush4 M = *(const ush4*)(rp + icb);
                ush4 R = *(const ush4*)(rp + icb + 4);
#pragma unroll
                for (int i = 0; i < 4; i++) { r[i] = bf2f(M[i]); r[4 + i] = bf2f(R[i]); }
            }
#pragma unroll
            for (int i = 0; i < 8; i++) sq[1 + i] = T(r[i]);
            if (icb > 0) {
                float e = F32 ? (float)rp[icb - 1] : bf2f(*(const u16*)(rp + icb - 1));
                sq[0] = T(e);
            } else sq[0] = 0.f;
        }
#pragma unroll
        for (int j = 0; j < 4; j++) {
            int kh = rin - S * j;
            if (kh < 0 || kh > 2) continue;
#pragma unroll
            for (int cc = 0; cc < 4; cc++)
#pragma unroll
                for (int kw = 0; kw < 3; kw++)
                    acc[j][cc] = fmaf(wv[kh * 3 + kw], sq[S * cc + kw], acc[j][cc]);
        }
    }

    // store bf16 + fused stats (fp32 from accumulators)
    u16* ob = out + (size_t)plane * (OHW * OHW) + (size_t)r0 * OHW + ct * 4;
    float s = 0.f, q = 0.f;
#pragma unroll
    for (int j = 0; j < 4; j++) {
        ush4 o;
#pragma unroll
        for (int cc = 0; cc < 4; cc++) {
            float v = acc[j][cc];
            o[cc] = f2bf(v);
            s += v;
            q = fmaf(v, v, q);
        }
        *(ush4*)(ob + (size_t)j * OHW) = o;
    }
#pragma unroll
    for (int m = G / 2; m >= 1; m >>= 1) { s += __shfl_xor(s, m); q += __shfl_xor(q, m); }
    if ((threadIdx.x & (G - 1)) == 0) {
        unsigned bin = blockIdx.x & (NBINS - 1);
        atomicAdd(&bsum[bin * C + c], s);
        atomicAdd(&bsq [bin * C + c], q);
    }
}

// ---- pointwise 1x1 conv via bf16 MFMA, bf16 in/out, fused BN+ReLU + stats ----
template<int CIN, int COUT, int HW>
__global__ __launch_bounds__(256, 4) void pwmfma_k(
    const u16* __restrict__ in, u16* __restrict__ out,
    const u16* __restrict__ wswz, const float* __restrict__ bias,
    const float* __restrict__ sc, const float* __restrict__ sh,
    float* __restrict__ bsum, float* __restrict__ bsq)
{
    constexpr int NK = CIN / 32;    // K-steps
    constexpr int NT = COUT / 16;   // co tiles
    __shared__ u16 frag[4 * NK * 512];       // [pxgrp][ks][lane][8] bf16
    __shared__ float lsum[4 * COUT];
    __shared__ float lsq [4 * COUT];

    const int tid = threadIdx.x;
    const size_t pixbase = (size_t)blockIdx.x * 64;   // HW % 64 == 0
    const int n  = (int)(pixbase / HW);
    const int p0 = (int)(pixbase % HW);
    const u16* ipb = in + ((size_t)n * CIN) * HW + p0;

    // ---- stage X tile [CIN][64px]: BN+ReLU, cvt bf16, write frag-order ----
    {
        const int pxo = (tid & 15) * 4;       // 4-aligned px offset in tile
        const int pg  = pxo >> 4;
        const int ci0 = (tid >> 4) * 2;       // even ci in [0,32)
        for (int cs = 0; cs < CIN; cs += 32) {
            int ci = cs + ci0;
            ush4 xa = *(const ush4*)(ipb + (size_t)ci * HW + pxo);
            ush4 xb = *(const ush4*)(ipb + (size_t)(ci + 1) * HW + pxo);
            float sa = sc[ci],     ha = sh[ci];
            float sb = sc[ci + 1], hb = sh[ci + 1];
            float a0 = relu(fmaf(bf2f(xa[0]), sa, ha)), a1 = relu(fmaf(bf2f(xa[1]), sa, ha));
            float a2 = relu(fmaf(bf2f(xa[2]), sa, ha)), a3 = relu(fmaf(bf2f(xa[3]), sa, ha));
            float b0 = relu(fmaf(bf2f(xb[0]), sb, hb)), b1 = relu(fmaf(bf2f(xb[1]), sb, hb));
            float b2 = relu(fmaf(bf2f(xb[2]), sb, hb)), b3 = relu(fmaf(bf2f(xb[3]), sb, hb));
            int ks = ci >> 5;
            int g  = (ci & 31) >> 3;
            int i0 = ci & 7;                  // even
            int bu = ((pg * NK + ks) * 64 + g * 16 + (pxo & 15)) * 8 + i0;
            *(u32*)&frag[bu]      = (u32)f2bf(a0) | ((u32)f2bf(b0) << 16);
            *(u32*)&frag[bu + 8]  = (u32)f2bf(a1) | ((u32)f2bf(b1) << 16);
            *(u32*)&frag[bu + 16] = (u32)f2bf(a2) | ((u32)f2bf(b2) << 16);
            *(u32*)&frag[bu + 24] = (u32)f2bf(a3) | ((u32)f2bf(b3) << 16);
        }
    }
    __syncthreads();

    // ---- MFMA K-loop: wave wv owns px-group wv (16 px) x all COUT ----
    const int wv   = tid >> 6;
    const int lane = tid & 63;
    f32x4 acc[NT];
#pragma unroll
    for (int t = 0; t < NT; t++) acc[t] = (f32x4){0.f, 0.f, 0.f, 0.f};

    const short8* wp = (const short8*)wswz;
#pragma unroll
    for (int ks = 0; ks < NK; ks++) {
        short8 bf = *(const short8*)&frag[((wv * NK + ks) * 64 + lane) * 8];
#pragma unroll
        for (int t = 0; t < NT; t++) {
            short8 af = wp[(ks * NT + t) * 64 + lane];
            acc[t] = __builtin_amdgcn_mfma_f32_16x16x32_bf16(af, bf, acc[t], 0, 0, 0);
        }
    }

    // ---- epilogue: bias, store bf16, fused stats ----
    const int g   = lane >> 4;
    const int col = lane & 15;
    const int p   = p0 + wv * 16 + col;
    const unsigned bin = blockIdx.x & (NBINS - 1);
#pragma unroll
    for (int t = 0; t < NT; t++) {
#pragma unroll
        for (int i = 0; i < 4; i++) {
            int co = t * 16 + g * 4 + i;
            float v = acc[t][i] + bias[co];
            out[((size_t)n * COUT + co) * HW + p] = f2bf(v);
            float s = v, q = v * v;
            s += __shfl_xor(s, 1); q += __shfl_xor(q, 1);
            s += __shfl_xor(s, 2); q += __shfl_xor(q, 2);
            s += __shfl_xor(s, 4); q += __shfl_xor(q, 4);
            s += __shfl_xor(s, 8); q += __shfl_xor(q, 8);
            if (col == 0) { lsum[wv * COUT + co] = s; lsq[wv * COUT + co] = q; }
        }
    }
    __syncthreads();
    if (tid < COUT) {
        float s = lsum[tid] + lsum[COUT + tid] + lsum[2 * COUT + tid] + lsum[3 * COUT + tid];
        float q = lsq[tid]  + lsq[COUT + tid]  + lsq[2 * COUT + tid]  + lsq[3 * COUT + tid];
        atomicAdd(&bsum[bin * COUT + tid], s);
        atomicAdd(&bsq [bin * COUT + tid], q);
    }
}

// ---- finalize BN: scale/shift from binned sums ----
__global__ void finalize_k(const float* __restrict__ bsum, const float* __restrict__ bsq,
                           const float* __restrict__ gamma, const float* __restrict__ beta,
                           float* __restrict__ sc, float* __restrict__ sh,
                           int C, float invcnt)
{
    int c = threadIdx.x;
    if (c >= C) return;
    float s = 0.f, q = 0.f;
    for (int b = 0; b < NBINS; b++) {
        s += bsum[b * C + c];
        q += bsq [b * C + c];
    }
    float m   = s * invcnt;
    float var = fmaf(q, invcnt, -m * m);
    float is  = gamma[c] * rsqrtf(var + EPSV);
    sc[c] = is;
    sh[c] = fmaf(-m, is, beta[c]);
}

// ---- final: BN+ReLU + global average pool (bf16 in, f32 out) ----
template<int HW>
__global__ __launch_bounds__(256) void avgpool_k(
    const u16* __restrict__ t, const float* __restrict__ sc, const float* __restrict__ sh,
    float* __restrict__ out, int C)
{
    int nc = blockIdx.x;
    int c = nc % C;
    float scv = sc[c], shv = sh[c];
    const u16* pl = t + (size_t)nc * HW;
    float s = 0.f;
    for (int p = threadIdx.x * 8; p < HW; p += 2048) {
        ush8 v = *(const ush8*)(pl + p);
#pragma unroll
        for (int i = 0; i < 8; i++) s += relu(fmaf(bf2f(v[i]), scv, shv));
    }
    int lane = threadIdx.x & 63, wid = threadIdx.x >> 6;
#pragma unroll
    for (int o = 32; o; o >>= 1) s += __shfl_down(s, o);
    __shared__ float red[4];
    if (lane == 0) red[wid] = s;
    __syncthreads();
    if (threadIdx.x == 0) out[nc] = (red[0] + red[1] + red[2] + red[3]) * (1.f / HW);
}

extern "C" void kernel_launch(void* const* d_in, const int* in_sizes, int n_in,
                              void* d_out, int out_size, void* d_ws, size_t ws_size,
                              hipStream_t stream)
{
    const float* x = (const float*)d_in[0];
    const float* P[3][8];
    for (int b = 0; b < 3; b++)
        for (int j = 0; j < 8; j++)
            P[b][j] = (const float*)d_in[1 + b * 8 + j];

    float* ws = (float*)d_ws;
    float* stats = ws;                       // 6 * 16384 f32
    float* scsh  = ws + 6 * 16384;           // 1536 f32
    u16*  wswz0  = (u16*)(scsh + 1536);      // 2048 u16
    u16*  wswz1  = wswz0 + 2048;             // 8192 u16
    u16*  wswz2  = wswz1 + 8192;             // 16384 u16
    u16*  A      = wswz2 + 16384;            // up to 12,845,056 bf16 (16B aligned)
    u16*  B      = A + 13000000;             // up to 25,690,112 bf16 (16B aligned)

    float* out = (float*)d_out;

    hipMemsetAsync(stats, 0, 6 * 16384 * sizeof(float), stream);
    prep_k<<<13, 256, 0, stream>>>(P[0][4], P[1][4], P[2][4], wswz0, wswz1, wswz2);

#define BSUM(i) (stats + (i) * 16384)
#define BSQ(i)  (stats + (i) * 16384 + 8192)
#define SC(i)   (scsh + (i) * 256)
#define SH(i)   (scsh + (i) * 256 + 128)

    const float inv1 = 1.f / (32.f * 12544.f);
    const float inv2 = 1.f / (32.f * 3136.f);

    // ---- block 0: 32 -> 64, stride 1, 112x112 ----
    dwtile_k<1, 112, 112, 32, false, 16, float><<<3136, 256, 0, stream>>>(
        x, A, P[0][0], P[0][1], nullptr, nullptr, BSUM(0), BSQ(0));
    finalize_k<<<1, 128, 0, stream>>>(BSUM(0), BSQ(0), P[0][2], P[0][3], SC(0), SH(0), 32, inv1);

    pwmfma_k<32, 64, 12544><<<6272, 256, 0, stream>>>(
        A, B, wswz0, P[0][5], SC(0), SH(0), BSUM(1), BSQ(1));
    finalize_k<<<1, 128, 0, stream>>>(BSUM(1), BSQ(1), P[0][6], P[0][7], SC(1), SH(1), 64, inv1);

    // ---- block 1: 64 -> 128, stride 2, 112 -> 56 ----
    dwtile_k<2, 112, 56, 64, true, 4, u16><<<1568, 256, 0, stream>>>(
        B, A, P[1][0], P[1][1], SC(1), SH(1), BSUM(2), BSQ(2));
    finalize_k<<<1, 128, 0, stream>>>(BSUM(2), BSQ(2), P[1][2], P[1][3], SC(2), SH(2), 64, inv2);

    pwmfma_k<64, 128, 3136><<<1568, 256, 0, stream>>>(
        A, B, wswz1, P[1][5], SC(2), SH(2), BSUM(3), BSQ(3));
    finalize_k<<<1, 128, 0, stream>>>(BSUM(3), BSQ(3), P[1][6], P[1][7], SC(3), SH(3), 128, inv2);

    // ---- block 2: 128 -> 128, stride 1, 56x56 ----
    dwtile_k<1, 56, 56, 128, true, 4, u16><<<3136, 256, 0, stream>>>(
        B, A, P[2][0], P[2][1], SC(3), SH(3), BSUM(4), BSQ(4));
    finalize_k<<<1, 128, 0, stream>>>(BSUM(4), BSQ(4), P[2][2], P[2][3], SC(4), SH(4), 128, inv2);

    pwmfma_k<128, 128, 3136><<<1568, 256, 0, stream>>>(
        A, B, wswz2, P[2][5], SC(4), SH(4), BSUM(5), BSQ(5));
    finalize_k<<<1, 128, 0, stream>>>(BSUM(5), BSQ(5), P[2][6], P[2][7], SC(5), SH(5), 128, inv2);

    // ---- final BN+ReLU + global average pool ----
    avgpool_k<3136><<<4096, 256, 0, stream>>>(B, SC(5), SH(5), out, 128);

#undef BSUM
#undef BSQ
#undef SC
#undef SH
}

// Round 6
// 205.525 us; speedup vs baseline: 4.0552x; 1.2047x over previous
//
#include <hip/hip_runtime.h>

#define EPSV 1e-5f
#define NBINS 64

typedef unsigned short u16;
typedef unsigned int u32;
typedef __attribute__((ext_vector_type(4))) unsigned short ush4;
typedef __attribute__((ext_vector_type(8))) unsigned short ush8;
typedef __attribute__((ext_vector_type(8))) short short8;
typedef __attribute__((ext_vector_type(4))) float f32x4;

__device__ __forceinline__ float relu(float x) { return fmaxf(x, 0.f); }

// fp32 -> bf16 round-to-nearest-even (finite values only)
__device__ __forceinline__ u16 f2bf(float f) {
    u32 u = __builtin_bit_cast(u32, f);
    u32 r = (u + 0x7fffu + ((u >> 16) & 1u)) >> 16;
    return (u16)r;
}
__device__ __forceinline__ float bf2f(u16 v) {
    return __builtin_bit_cast(float, (u32)v << 16);
}

// ---- prep: swizzle pw weights into fragment order (lane=co, k-groups of 8 ci) ----
template<int CIN, int COUT>
__device__ __forceinline__ void prep_one(const float* __restrict__ w,
                                         u16* __restrict__ dst, int widx) {
    const int NT = COUT / 16;
    int lane = widx & 63;
    int t  = (widx >> 6) % NT;
    int ks = (widx >> 6) / NT;
    int co  = t * 16 + (lane & 15);
    int ci0 = ks * 32 + (lane >> 4) * 8;
#pragma unroll
    for (int i = 0; i < 8; i++)
        dst[(size_t)widx * 8 + i] = f2bf(w[co * CIN + ci0 + i]);
}

__global__ void prep_k(const float* __restrict__ w0, const float* __restrict__ w1,
                       const float* __restrict__ w2, u16* __restrict__ s0,
                       u16* __restrict__ s1, u16* __restrict__ s2) {
    int i = blockIdx.x * 256 + threadIdx.x;          // 3328 words total
    if (i < 256)       prep_one<32, 64>  (w0, s0, i);
    else if (i < 1280) prep_one<64, 128> (w1, s1, i - 256);
    else if (i < 3328) prep_one<128, 128>(w2, s2, i - 1280);
}

// ---- depthwise 3x3 pad 1: 4x4 output tile per thread, fused stats ----
template<int S, int IHW, int OHW, int C, bool BNIN, int G, typename TIN>
__global__ __launch_bounds__(256) void dwtile_k(
    const TIN* __restrict__ in, u16* __restrict__ out,
    const float* __restrict__ w9, const float* __restrict__ bias,
    const float* __restrict__ sc, const float* __restrict__ sh,
    float* __restrict__ bsum, float* __restrict__ bsq)
{
    constexpr bool F32 = sizeof(TIN) == 4;
    constexpr int CT = OHW / 4;
    constexpr int TPP = CT * CT;
    constexpr int NR = 3 + 3 * S;
    constexpr int NQ = 3 + 3 * S;

    int t = blockIdx.x * 256 + threadIdx.x;
    int plane = t / TPP;
    int w = t % TPP;
    int rt = w / CT, ct = w % CT;
    int c = plane & (C - 1);

    const TIN* base = in + (size_t)plane * (IHW * IHW);
    float scv = 1.f, shv = 0.f;
    if (BNIN) { scv = sc[c]; shv = sh[c]; }
    float wv[9];
#pragma unroll
    for (int k = 0; k < 9; k++) wv[k] = w9[c * 9 + k];
    float bz = bias[c];

    float acc[4][4];
#pragma unroll
    for (int j = 0; j < 4; j++)
#pragma unroll
        for (int cc = 0; cc < 4; cc++) acc[j][cc] = bz;

    const int r0 = rt * 4;
    const int icb = ct * 4 * S;

    auto T = [&](float v) { return BNIN ? relu(fmaf(v, scv, shv)) : v; };

#pragma unroll
    for (int rin = 0; rin < NR; rin++) {
        int ih = r0 * S + rin - 1;
        if (ih < 0 || ih >= IHW) continue;
        const TIN* rp = base + (size_t)ih * IHW;
        float sq[NQ];
        if constexpr (S == 1) {
            float r1, r2, r3, r4;
            if constexpr (F32) {
                float4 M = *(const float4*)(rp + icb);
                r1 = M.x; r2 = M.y; r3 = M.z; r4 = M.w;
            } else {
                ush4 M = *(const ush4*)(rp + icb);
                r1 = bf2f(M[0]); r2 = bf2f(M[1]); r3 = bf2f(M[2]); r4 = bf2f(M[3]);
            }
            sq[1] = T(r1); sq[2] = T(r2); sq[3] = T(r3); sq[4] = T(r4);
            if (icb > 0) {
                float e = F32 ? (float)rp[icb - 1] : bf2f(*(const u16*)(rp + icb - 1));
                sq[0] = T(e);
            } else sq[0] = 0.f;
            if (icb + 4 < IHW) {
                float e = F32 ? (float)rp[icb + 4] : bf2f(*(const u16*)(rp + icb + 4));
                sq[5] = T(e);
            } else sq[5] = 0.f;
        } else {
            float r[8];
            if constexpr (F32) {
                float4 M = *(const float4*)(rp + icb);
                float4 R = *(const float4*)(rp + icb + 4);
                r[0] = M.x; r[1] = M.y; r[2] = M.z; r[3] = M.w;
                r[4] = R.x; r[5] = R.y; r[6] = R.z; r[7] = R.w;
            } else {
                ush4 M = *(const ush4*)(rp + icb);
                ush4 R = *(const ush4*)(rp + icb + 4);
#pragma unroll
                for (int i = 0; i < 4; i++) { r[i] = bf2f(M[i]); r[4 + i] = bf2f(R[i]); }
            }
#pragma unroll
            for (int i = 0; i < 8; i++) sq[1 + i] = T(r[i]);
            if (icb > 0) {
                float e = F32 ? (float)rp[icb - 1] : bf2f(*(const u16*)(rp + icb - 1));
                sq[0] = T(e);
            } else sq[0] = 0.f;
        }
#pragma unroll
        for (int j = 0; j < 4; j++) {
            int kh = rin - S * j;
            if (kh < 0 || kh > 2) continue;
#pragma unroll
            for (int cc = 0; cc < 4; cc++)
#pragma unroll
                for (int kw = 0; kw < 3; kw++)
                    acc[j][cc] = fmaf(wv[kh * 3 + kw], sq[S * cc + kw], acc[j][cc]);
        }
    }

    u16* ob = out + (size_t)plane * (OHW * OHW) + (size_t)r0 * OHW + ct * 4;
    float s = 0.f, q = 0.f;
#pragma unroll
    for (int j = 0; j < 4; j++) {
        ush4 o;
#pragma unroll
        for (int cc = 0; cc < 4; cc++) {
            float v = acc[j][cc];
            o[cc] = f2bf(v);
            s += v;
            q = fmaf(v, v, q);
        }
        *(ush4*)(ob + (size_t)j * OHW) = o;
    }
#pragma unroll
    for (int m = G / 2; m >= 1; m >>= 1) { s += __shfl_xor(s, m); q += __shfl_xor(q, m); }
    if ((threadIdx.x & (G - 1)) == 0) {
        unsigned bin = blockIdx.x & (NBINS - 1);
        atomicAdd(&bsum[bin * C + c], s);
        atomicAdd(&bsq [bin * C + c], q);
    }
}

// ---- pointwise 1x1 conv via bf16 MFMA (X = A-operand, W = B-operand) ----
// D[m=px][n=co]: lane holds 4 consecutive px (regs) at co = t*16 + (lane&15).
// Stats: per-lane pixel partials + 2 shuffles; stores vectorized ush4.
template<int CIN, int COUT, int HW>
__global__ __launch_bounds__(256, 4) void pwmfma_k(
    const u16* __restrict__ in, u16* __restrict__ out,
    const u16* __restrict__ wswz, const float* __restrict__ bias,
    const float* __restrict__ sc, const float* __restrict__ sh,
    float* __restrict__ bsum, float* __restrict__ bsq)
{
    constexpr int NK = CIN / 32;    // K-steps
    constexpr int NT = COUT / 16;   // co tiles
    constexpr int ROWSTRIDE = NK * 512 + 8;   // u16; +16B pad per px-group row
    __shared__ u16 frag[4 * ROWSTRIDE];
    __shared__ float lsum[4 * COUT];
    __shared__ float lsq [4 * COUT];

    const int tid = threadIdx.x;
    const size_t pixbase = (size_t)blockIdx.x * 64;   // HW % 64 == 0
    const int n  = (int)(pixbase / HW);
    const int p0 = (int)(pixbase % HW);

    // ---- stage X tile [64px][CIN] as A-fragments: BN+ReLU + cvt bf16 ----
    {
        const int px = tid & 63;
        const int kq = tid >> 6;              // k-group-of-8 within 32-chunk
        const u16* ipx = in + (size_t)n * CIN * HW + p0 + px;
#pragma unroll
        for (int ks = 0; ks < NK; ks++) {
            const int ci0 = (ks * 4 + kq) * 8;
            short8 pkd;
#pragma unroll
            for (int j = 0; j < 8; j++) {
                float v = relu(fmaf(bf2f(ipx[(size_t)(ci0 + j) * HW]), sc[ci0 + j], sh[ci0 + j]));
                pkd[j] = (short)f2bf(v);
            }
            *(short8*)&frag[(size_t)(px >> 4) * ROWSTRIDE + ks * 512 + ((px & 15) + 16 * kq) * 8] = pkd;
        }
    }
    __syncthreads();

    // ---- MFMA K-loop: wave wv owns px-group wv (16 px) x all COUT ----
    const int wv   = tid >> 6;
    const int lane = tid & 63;
    f32x4 acc[NT];
#pragma unroll
    for (int t = 0; t < NT; t++) acc[t] = (f32x4){0.f, 0.f, 0.f, 0.f};

    const short8* wp = (const short8*)wswz;
#pragma unroll
    for (int ks = 0; ks < NK; ks++) {
        short8 af = *(const short8*)&frag[(size_t)wv * ROWSTRIDE + ks * 512 + lane * 8];
#pragma unroll
        for (int t = 0; t < NT; t++) {
            short8 bf = wp[(ks * NT + t) * 64 + lane];
            acc[t] = __builtin_amdgcn_mfma_f32_16x16x32_bf16(af, bf, acc[t], 0, 0, 0);
        }
    }

    // ---- epilogue: bias, vectorized store, cheap stats ----
    const int col  = lane & 15;               // co offset within tile
    const int prow = (lane >> 4) * 4;         // px offset of reg 0
    const int p    = p0 + wv * 16 + prow;
#pragma unroll
    for (int t = 0; t < NT; t++) {
        int co = t * 16 + col;
        float bz = bias[co];
        float v0 = acc[t][0] + bz, v1 = acc[t][1] + bz;
        float v2 = acc[t][2] + bz, v3 = acc[t][3] + bz;
        ush4 o = {f2bf(v0), f2bf(v1), f2bf(v2), f2bf(v3)};
        *(ush4*)(out + ((size_t)n * COUT + co) * HW + p) = o;
        float s = (v0 + v1) + (v2 + v3);
        float q = fmaf(v0, v0, fmaf(v1, v1, fmaf(v2, v2, v3 * v3)));
        s += __shfl_xor(s, 16); q += __shfl_xor(q, 16);
        s += __shfl_xor(s, 32); q += __shfl_xor(q, 32);
        if (lane < 16) { lsum[wv * COUT + co] = s; lsq[wv * COUT + co] = q; }
    }
    __syncthreads();
    if (tid < COUT) {
        const unsigned bin = blockIdx.x & (NBINS - 1);
        float s = lsum[tid] + lsum[COUT + tid] + lsum[2 * COUT + tid] + lsum[3 * COUT + tid];
        float q = lsq[tid]  + lsq[COUT + tid]  + lsq[2 * COUT + tid]  + lsq[3 * COUT + tid];
        atomicAdd(&bsum[bin * COUT + tid], s);
        atomicAdd(&bsq [bin * COUT + tid], q);
    }
}

// ---- finalize BN: scale/shift from binned sums ----
__global__ void finalize_k(const float* __restrict__ bsum, const float* __restrict__ bsq,
                           const float* __restrict__ gamma, const float* __restrict__ beta,
                           float* __restrict__ sc, float* __restrict__ sh,
                           int C, float invcnt)
{
    int c = threadIdx.x;
    if (c >= C) return;
    float s = 0.f, q = 0.f;
    for (int b = 0; b < NBINS; b++) {
        s += bsum[b * C + c];
        q += bsq [b * C + c];
    }
    float m   = s * invcnt;
    float var = fmaf(q, invcnt, -m * m);
    float is  = gamma[c] * rsqrtf(var + EPSV);
    sc[c] = is;
    sh[c] = fmaf(-m, is, beta[c]);
}

// ---- final: BN+ReLU + global average pool (bf16 in, f32 out) ----
template<int HW>
__global__ __launch_bounds__(256) void avgpool_k(
    const u16* __restrict__ t, const float* __restrict__ sc, const float* __restrict__ sh,
    float* __restrict__ out, int C)
{
    int nc = blockIdx.x;
    int c = nc % C;
    float scv = sc[c], shv = sh[c];
    const u16* pl = t + (size_t)nc * HW;
    float s = 0.f;
    for (int p = threadIdx.x * 8; p < HW; p += 2048) {
        ush8 v = *(const ush8*)(pl + p);
#pragma unroll
        for (int i = 0; i < 8; i++) s += relu(fmaf(bf2f(v[i]), scv, shv));
    }
    int lane = threadIdx.x & 63, wid = threadIdx.x >> 6;
#pragma unroll
    for (int o = 32; o; o >>= 1) s += __shfl_down(s, o);
    __shared__ float red[4];
    if (lane == 0) red[wid] = s;
    __syncthreads();
    if (threadIdx.x == 0) out[nc] = (red[0] + red[1] + red[2] + red[3]) * (1.f / HW);
}

extern "C" void kernel_launch(void* const* d_in, const int* in_sizes, int n_in,
                              void* d_out, int out_size, void* d_ws, size_t ws_size,
                              hipStream_t stream)
{
    const float* x = (const float*)d_in[0];
    const float* P[3][8];
    for (int b = 0; b < 3; b++)
        for (int j = 0; j < 8; j++)
            P[b][j] = (const float*)d_in[1 + b * 8 + j];

    float* ws = (float*)d_ws;
    float* stats = ws;                       // 6 * 16384 f32
    float* scsh  = ws + 6 * 16384;           // 1536 f32
    u16*  wswz0  = (u16*)(scsh + 1536);      // 2048 u16
    u16*  wswz1  = wswz0 + 2048;             // 8192 u16
    u16*  wswz2  = wswz1 + 8192;             // 16384 u16
    u16*  A      = wswz2 + 16384;            // up to 12,845,056 bf16 (16B aligned)
    u16*  B      = A + 13000000;             // up to 25,690,112 bf16 (16B aligned)

    float* out = (float*)d_out;

    hipMemsetAsync(stats, 0, 6 * 16384 * sizeof(float), stream);
    prep_k<<<13, 256, 0, stream>>>(P[0][4], P[1][4], P[2][4], wswz0, wswz1, wswz2);

#define BSUM(i) (stats + (i) * 16384)
#define BSQ(i)  (stats + (i) * 16384 + 8192)
#define SC(i)   (scsh + (i) * 256)
#define SH(i)   (scsh + (i) * 256 + 128)

    const float inv1 = 1.f / (32.f * 12544.f);
    const float inv2 = 1.f / (32.f * 3136.f);

    // ---- block 0: 32 -> 64, stride 1, 112x112 ----
    dwtile_k<1, 112, 112, 32, false, 16, float><<<3136, 256, 0, stream>>>(
        x, A, P[0][0], P[0][1], nullptr, nullptr, BSUM(0), BSQ(0));
    finalize_k<<<1, 128, 0, stream>>>(BSUM(0), BSQ(0), P[0][2], P[0][3], SC(0), SH(0), 32, inv1);

    pwmfma_k<32, 64, 12544><<<6272, 256, 0, stream>>>(
        A, B, wswz0, P[0][5], SC(0), SH(0), BSUM(1), BSQ(1));
    finalize_k<<<1, 128, 0, stream>>>(BSUM(1), BSQ(1), P[0][6], P[0][7], SC(1), SH(1), 64, inv1);

    // ---- block 1: 64 -> 128, stride 2, 112 -> 56 ----
    dwtile_k<2, 112, 56, 64, true, 4, u16><<<1568, 256, 0, stream>>>(
        B, A, P[1][0], P[1][1], SC(1), SH(1), BSUM(2), BSQ(2));
    finalize_k<<<1, 128, 0, stream>>>(BSUM(2), BSQ(2), P[1][2], P[1][3], SC(2), SH(2), 64, inv2);

    pwmfma_k<64, 128, 3136><<<1568, 256, 0, stream>>>(
        A, B, wswz1, P[1][5], SC(2), SH(2), BSUM(3), BSQ(3));
    finalize_k<<<1, 128, 0, stream>>>(BSUM(3), BSQ(3), P[1][6], P[1][7], SC(3), SH(3), 128, inv2);

    // ---- block 2: 128 -> 128, stride 1, 56x56 ----
    dwtile_k<1, 56, 56, 128, true, 4, u16><<<3136, 256, 0, stream>>>(
        B, A, P[2][0], P[2][1], SC(3), SH(3), BSUM(4), BSQ(4));
    finalize_k<<<1, 128, 0, stream>>>(BSUM(4), BSQ(4), P[2][2], P[2][3], SC(4), SH(4), 128, inv2);

    pwmfma_k<128, 128, 3136><<<1568, 256, 0, stream>>>(
        A, B, wswz2, P[2][5], SC(4), SH(4), BSUM(5), BSQ(5));
    finalize_k<<<1, 128, 0, stream>>>(BSUM(5), BSQ(5), P[2][6], P[2][7], SC(5), SH(5), 128, inv2);

    // ---- final BN+ReLU + global average pool ----
    avgpool_k<3136><<<4096, 256, 0, stream>>>(B, SC(5), SH(5), out, 128);

#undef BSUM
#undef BSQ
#undef SC
#undef SH
}

// Round 7
// 180.447 us; speedup vs baseline: 4.6188x; 1.1390x over previous
//
#include <hip/hip_runtime.h>

#define EPSV 1e-5f
#define NBINS 32

typedef unsigned short u16;
typedef unsigned int u32;
typedef __attribute__((ext_vector_type(4))) unsigned short ush4;
typedef __attribute__((ext_vector_type(8))) unsigned short ush8;
typedef __attribute__((ext_vector_type(8))) short short8;
typedef __attribute__((ext_vector_type(4))) float f32x4;

__device__ __forceinline__ float relu(float x) { return fmaxf(x, 0.f); }

__device__ __forceinline__ u16 f2bf(float f) {
    u32 u = __builtin_bit_cast(u32, f);
    u32 r = (u + 0x7fffu + ((u >> 16) & 1u)) >> 16;
    return (u16)r;
}
__device__ __forceinline__ float bf2f(u16 v) {
    return __builtin_bit_cast(float, (u32)v << 16);
}

// ---- prep: zero stat bins + swizzle pw weights into fragment order ----
template<int CIN, int COUT>
__device__ __forceinline__ void prep_one(const float* __restrict__ w,
                                         u16* __restrict__ dst, int widx) {
    const int NT = COUT / 16;
    int lane = widx & 63;
    int t  = (widx >> 6) % NT;
    int ks = (widx >> 6) / NT;
    int co  = t * 16 + (lane & 15);
    int ci0 = ks * 32 + (lane >> 4) * 8;
#pragma unroll
    for (int i = 0; i < 8; i++)
        dst[(size_t)widx * 8 + i] = f2bf(w[co * CIN + ci0 + i]);
}

__global__ void prep_k(const float* __restrict__ w0, const float* __restrict__ w1,
                       const float* __restrict__ w2, u16* __restrict__ s0,
                       u16* __restrict__ s1, u16* __restrict__ s2,
                       float* __restrict__ bins) {
    int i = blockIdx.x * 256 + threadIdx.x;          // 3328 threads
    for (int z = i; z < 6 * 2 * NBINS * 128; z += 3328) bins[z] = 0.f;
    if (i < 256)       prep_one<32, 64>  (w0, s0, i);
    else if (i < 1280) prep_one<64, 128> (w1, s1, i - 256);
    else if (i < 3328) prep_one<128, 128>(w2, s2, i - 1280);
}

// ---- depthwise 3x3 pad 1 stride 1, LDS-staged band, fused finalize+stats ----
// Block = one (plane, band of BR output rows). Stage (BR+2) x IHW into LDS with
// BN+ReLU applied; compute 8 px/thread from LDS; one stats atomic per block.
template<int IHW, int C, bool BNIN, int BR, int LST, typename TIN>
__global__ __launch_bounds__(256) void dwlds_k(
    const TIN* __restrict__ in, u16* __restrict__ out,
    const float* __restrict__ w9, const float* __restrict__ bias,
    const float* __restrict__ gamma, const float* __restrict__ beta,
    const float* __restrict__ bsum_in, const float* __restrict__ bsq_in,
    float invcnt_in, float* __restrict__ bsum, float* __restrict__ bsq)
{
    constexpr bool F32 = sizeof(TIN) == 4;
    constexpr int NB  = IHW / BR;          // bands per plane
    constexpr int TPR = IHW / 8;           // compute threads per row
    constexpr int NACT = BR * TPR;
    constexpr int W4 = IHW / 4;
    __shared__ float tile[(BR + 2) * LST];
    __shared__ float bnss[2];
    __shared__ float redbuf[8];

    const int bid = blockIdx.x;
    const int plane = bid / NB;
    const int band  = bid % NB;
    const int c = plane & (C - 1);
    const int tid = threadIdx.x;

    // folded BN finalize for this block's single input channel
    if (BNIN) {
        if (tid < NBINS) {
            float s = bsum_in[tid * C + c];
            float q = bsq_in [tid * C + c];
#pragma unroll
            for (int m = NBINS / 2; m >= 1; m >>= 1) {
                s += __shfl_xor(s, m); q += __shfl_xor(q, m);
            }
            if (tid == 0) {
                float mm  = s * invcnt_in;
                float var = fmaf(q, invcnt_in, -mm * mm);
                float is  = gamma[c] * rsqrtf(var + EPSV);
                bnss[0] = is; bnss[1] = fmaf(-mm, is, beta[c]);
            }
        }
        __syncthreads();
    }
    const float scv = BNIN ? bnss[0] : 1.f;
    const float shv = BNIN ? bnss[1] : 0.f;

    const int r0 = band * BR;
    const TIN* base = in + (size_t)plane * (IHW * IHW);

    // zero left/right pads
    for (int i = tid; i < (BR + 2) * 2; i += 256) {
        int r = i >> 1, side = i & 1;
        float4 z = {0.f, 0.f, 0.f, 0.f};
        *(float4*)&tile[r * LST + side * (IHW + 4)] = z;
    }
    // stage rows r0-1 .. r0+BR (BN+ReLU applied to in-range data; halo rows = 0)
    for (int i = tid; i < (BR + 2) * W4; i += 256) {
        int r = i / W4, c4 = (i % W4) * 4;
        int gr = r0 - 1 + r;
        float4 v = {0.f, 0.f, 0.f, 0.f};
        if (gr >= 0 && gr < IHW) {
            if constexpr (F32) {
                v = *(const float4*)(base + (size_t)gr * IHW + c4);
            } else {
                ush4 h = *(const ush4*)(base + (size_t)gr * IHW + c4);
                v = {bf2f(h[0]), bf2f(h[1]), bf2f(h[2]), bf2f(h[3])};
            }
            if (BNIN) {
                v.x = relu(fmaf(v.x, scv, shv)); v.y = relu(fmaf(v.y, scv, shv));
                v.z = relu(fmaf(v.z, scv, shv)); v.w = relu(fmaf(v.w, scv, shv));
            }
        }
        *(float4*)&tile[r * LST + 4 + c4] = v;
    }
    __syncthreads();

    float s = 0.f, q = 0.f;
    if (tid < NACT) {
        const int r  = tid / TPR;
        const int c0 = (tid % TPR) * 8;
        float wv[9];
#pragma unroll
        for (int k = 0; k < 9; k++) wv[k] = w9[c * 9 + k];
        float bz = bias[c];
        float a[8];
#pragma unroll
        for (int j = 0; j < 8; j++) a[j] = bz;
#pragma unroll
        for (int kr = 0; kr < 3; kr++) {
            const float* rp = &tile[(r + kr) * LST + 3 + c0];
            float v[10];
#pragma unroll
            for (int i = 0; i < 10; i++) v[i] = rp[i];
#pragma unroll
            for (int j = 0; j < 8; j++)
                a[j] = fmaf(wv[kr * 3], v[j],
                        fmaf(wv[kr * 3 + 1], v[j + 1],
                         fmaf(wv[kr * 3 + 2], v[j + 2], a[j])));
        }
        u16* ob = out + (size_t)plane * (IHW * IHW) + (size_t)(r0 + r) * IHW + c0;
        ush4 o0 = {f2bf(a[0]), f2bf(a[1]), f2bf(a[2]), f2bf(a[3])};
        ush4 o1 = {f2bf(a[4]), f2bf(a[5]), f2bf(a[6]), f2bf(a[7])};
        *(ush4*)ob = o0;
        *(ush4*)(ob + 4) = o1;
#pragma unroll
        for (int j = 0; j < 8; j++) { s += a[j]; q = fmaf(a[j], a[j], q); }
    }
    // block-level stats reduce -> one atomic pair
#pragma unroll
    for (int m = 32; m >= 1; m >>= 1) { s += __shfl_xor(s, m); q += __shfl_xor(q, m); }
    int lane = tid & 63, wid = tid >> 6;
    if (lane == 0) { redbuf[wid] = s; redbuf[4 + wid] = q; }
    __syncthreads();
    if (tid == 0) {
        s = redbuf[0] + redbuf[1] + redbuf[2] + redbuf[3];
        q = redbuf[4] + redbuf[5] + redbuf[6] + redbuf[7];
        unsigned bin = bid & (NBINS - 1);
        atomicAdd(&bsum[bin * C + c], s);
        atomicAdd(&bsq [bin * C + c], q);
    }
}

// ---- depthwise 3x3 pad 1 stride 2: 4x4 tile/thread, folded finalize+stats ----
template<int IHW, int OHW, int C, int G>
__global__ __launch_bounds__(256) void dwtile2_k(
    const u16* __restrict__ in, u16* __restrict__ out,
    const float* __restrict__ w9, const float* __restrict__ bias,
    const float* __restrict__ gamma, const float* __restrict__ beta,
    const float* __restrict__ bsum_in, const float* __restrict__ bsq_in,
    float invcnt_in, float* __restrict__ bsum, float* __restrict__ bsq)
{
    constexpr int S = 2;
    constexpr int CT = OHW / 4;
    constexpr int TPP = CT * CT;
    __shared__ float lsc[C], lsh[C];

    const int tid = threadIdx.x;
    for (int cc = tid; cc < C; cc += 256) {
        float s = 0.f, q = 0.f;
        for (int b = 0; b < NBINS; b++) {
            s += bsum_in[b * C + cc];
            q += bsq_in [b * C + cc];
        }
        float mm  = s * invcnt_in;
        float var = fmaf(q, invcnt_in, -mm * mm);
        float is  = gamma[cc] * rsqrtf(var + EPSV);
        lsc[cc] = is; lsh[cc] = fmaf(-mm, is, beta[cc]);
    }
    __syncthreads();

    int t = blockIdx.x * 256 + tid;
    int plane = t / TPP;
    int w = t % TPP;
    int rt = w / CT, ct = w % CT;
    int c = plane & (C - 1);

    const u16* base = in + (size_t)plane * (IHW * IHW);
    const float scv = lsc[c], shv = lsh[c];
    float wv[9];
#pragma unroll
    for (int k = 0; k < 9; k++) wv[k] = w9[c * 9 + k];
    float bz = bias[c];

    float acc[4][4];
#pragma unroll
    for (int j = 0; j < 4; j++)
#pragma unroll
        for (int cc = 0; cc < 4; cc++) acc[j][cc] = bz;

    const int r0 = rt * 4;
    const int icb = ct * 4 * S;

    auto T = [&](float v) { return relu(fmaf(v, scv, shv)); };

#pragma unroll
    for (int rin = 0; rin < 9; rin++) {
        int ih = r0 * S + rin - 1;
        if (ih < 0 || ih >= IHW) continue;
        const u16* rp = base + (size_t)ih * IHW;
        float sq[9];
        ush4 M = *(const ush4*)(rp + icb);
        ush4 R = *(const ush4*)(rp + icb + 4);
#pragma unroll
        for (int i = 0; i < 4; i++) { sq[1 + i] = T(bf2f(M[i])); sq[5 + i] = T(bf2f(R[i])); }
        sq[0] = (icb > 0) ? T(bf2f(rp[icb - 1])) : 0.f;
#pragma unroll
        for (int j = 0; j < 4; j++) {
            int kh = rin - S * j;
            if (kh < 0 || kh > 2) continue;
#pragma unroll
            for (int cc = 0; cc < 4; cc++)
#pragma unroll
                for (int kw = 0; kw < 3; kw++)
                    acc[j][cc] = fmaf(wv[kh * 3 + kw], sq[S * cc + kw], acc[j][cc]);
        }
    }

    u16* ob = out + (size_t)plane * (OHW * OHW) + (size_t)r0 * OHW + ct * 4;
    float s = 0.f, q = 0.f;
#pragma unroll
    for (int j = 0; j < 4; j++) {
        ush4 o;
#pragma unroll
        for (int cc = 0; cc < 4; cc++) {
            float v = acc[j][cc];
            o[cc] = f2bf(v);
            s += v;
            q = fmaf(v, v, q);
        }
        *(ush4*)(ob + (size_t)j * OHW) = o;
    }
#pragma unroll
    for (int m = G / 2; m >= 1; m >>= 1) { s += __shfl_xor(s, m); q += __shfl_xor(q, m); }
    if ((tid & (G - 1)) == 0) {
        unsigned bin = blockIdx.x & (NBINS - 1);
        atomicAdd(&bsum[bin * C + c], s);
        atomicAdd(&bsq [bin * C + c], q);
    }
}

// ---- pointwise 1x1 conv via bf16 MFMA (X=A, W=B), folded finalize + stats ----
template<int CIN, int COUT, int HW>
__global__ __launch_bounds__(256, 4) void pwmfma_k(
    const u16* __restrict__ in, u16* __restrict__ out,
    const u16* __restrict__ wswz, const float* __restrict__ bias,
    const float* __restrict__ gamma, const float* __restrict__ beta,
    const float* __restrict__ bsum_in, const float* __restrict__ bsq_in,
    float invcnt_in, float* __restrict__ bsum, float* __restrict__ bsq)
{
    constexpr int NK = CIN / 32;
    constexpr int NT = COUT / 16;
    constexpr int ROWSTRIDE = NK * 512 + 8;
    __shared__ u16 frag[4 * ROWSTRIDE];
    __shared__ float lsum[4 * COUT];
    __shared__ float lsq [4 * COUT];
    __shared__ float scs[CIN], shs[CIN];

    const int tid = threadIdx.x;

    // folded BN finalize for the CIN input channels
    if (tid < CIN) {
        float s = 0.f, q = 0.f;
        for (int b = 0; b < NBINS; b++) {
            s += bsum_in[b * CIN + tid];
            q += bsq_in [b * CIN + tid];
        }
        float mm  = s * invcnt_in;
        float var = fmaf(q, invcnt_in, -mm * mm);
        float is  = gamma[tid] * rsqrtf(var + EPSV);
        scs[tid] = is; shs[tid] = fmaf(-mm, is, beta[tid]);
    }
    __syncthreads();

    const size_t pixbase = (size_t)blockIdx.x * 64;   // HW % 64 == 0
    const int n  = (int)(pixbase / HW);
    const int p0 = (int)(pixbase % HW);

    // stage X tile [64px][CIN] as A-fragments: BN+ReLU + cvt bf16
    {
        const int px = tid & 63;
        const int kq = tid >> 6;
        const u16* ipx = in + (size_t)n * CIN * HW + p0 + px;
#pragma unroll
        for (int ks = 0; ks < NK; ks++) {
            const int ci0 = (ks * 4 + kq) * 8;
            short8 pkd;
#pragma unroll
            for (int j = 0; j < 8; j++) {
                float v = relu(fmaf(bf2f(ipx[(size_t)(ci0 + j) * HW]), scs[ci0 + j], shs[ci0 + j]));
                pkd[j] = (short)f2bf(v);
            }
            *(short8*)&frag[(size_t)(px >> 4) * ROWSTRIDE + ks * 512 + ((px & 15) + 16 * kq) * 8] = pkd;
        }
    }
    __syncthreads();

    const int wv   = tid >> 6;
    const int lane = tid & 63;
    f32x4 acc[NT];
#pragma unroll
    for (int t = 0; t < NT; t++) acc[t] = (f32x4){0.f, 0.f, 0.f, 0.f};

    const short8* wp = (const short8*)wswz;
#pragma unroll
    for (int ks = 0; ks < NK; ks++) {
        short8 af = *(const short8*)&frag[(size_t)wv * ROWSTRIDE + ks * 512 + lane * 8];
#pragma unroll
        for (int t = 0; t < NT; t++) {
            short8 bf = wp[(ks * NT + t) * 64 + lane];
            acc[t] = __builtin_amdgcn_mfma_f32_16x16x32_bf16(af, bf, acc[t], 0, 0, 0);
        }
    }

    const int col  = lane & 15;
    const int prow = (lane >> 4) * 4;
    const int p    = p0 + wv * 16 + prow;
#pragma unroll
    for (int t = 0; t < NT; t++) {
        int co = t * 16 + col;
        float bz = bias[co];
        float v0 = acc[t][0] + bz, v1 = acc[t][1] + bz;
        float v2 = acc[t][2] + bz, v3 = acc[t][3] + bz;
        ush4 o = {f2bf(v0), f2bf(v1), f2bf(v2), f2bf(v3)};
        *(ush4*)(out + ((size_t)n * COUT + co) * HW + p) = o;
        float s = (v0 + v1) + (v2 + v3);
        float q = fmaf(v0, v0, fmaf(v1, v1, fmaf(v2, v2, v3 * v3)));
        s += __shfl_xor(s, 16); q += __shfl_xor(q, 16);
        s += __shfl_xor(s, 32); q += __shfl_xor(q, 32);
        if (lane < 16) { lsum[wv * COUT + co] = s; lsq[wv * COUT + co] = q; }
    }
    __syncthreads();
    if (tid < COUT) {
        const unsigned bin = blockIdx.x & (NBINS - 1);
        float s = lsum[tid] + lsum[COUT + tid] + lsum[2 * COUT + tid] + lsum[3 * COUT + tid];
        float q = lsq[tid]  + lsq[COUT + tid]  + lsq[2 * COUT + tid]  + lsq[3 * COUT + tid];
        atomicAdd(&bsum[bin * COUT + tid], s);
        atomicAdd(&bsq [bin * COUT + tid], q);
    }
}

// ---- final: folded finalize + BN+ReLU + global average pool ----
template<int HW, int C>
__global__ __launch_bounds__(256) void avgpool_k(
    const u16* __restrict__ t,
    const float* __restrict__ gamma, const float* __restrict__ beta,
    const float* __restrict__ bsum_in, const float* __restrict__ bsq_in,
    float invcnt_in, float* __restrict__ out)
{
    __shared__ float bnss[2];
    __shared__ float red[4];
    int nc = blockIdx.x;
    int c = nc & (C - 1);
    int tid = threadIdx.x;

    if (tid < NBINS) {
        float s = bsum_in[tid * C + c];
        float q = bsq_in [tid * C + c];
#pragma unroll
        for (int m = NBINS / 2; m >= 1; m >>= 1) { s += __shfl_xor(s, m); q += __shfl_xor(q, m); }
        if (tid == 0) {
            float mm  = s * invcnt_in;
            float var = fmaf(q, invcnt_in, -mm * mm);
            float is  = gamma[c] * rsqrtf(var + EPSV);
            bnss[0] = is; bnss[1] = fmaf(-mm, is, beta[c]);
        }
    }
    __syncthreads();
    float scv = bnss[0], shv = bnss[1];

    const u16* pl = t + (size_t)nc * HW;
    float s = 0.f;
    for (int p = tid * 8; p < HW; p += 2048) {
        ush8 v = *(const ush8*)(pl + p);
#pragma unroll
        for (int i = 0; i < 8; i++) s += relu(fmaf(bf2f(v[i]), scv, shv));
    }
    int lane = tid & 63, wid = tid >> 6;
#pragma unroll
    for (int o = 32; o; o >>= 1) s += __shfl_down(s, o);
    if (lane == 0) red[wid] = s;
    __syncthreads();
    if (tid == 0) out[nc] = (red[0] + red[1] + red[2] + red[3]) * (1.f / HW);
}

extern "C" void kernel_launch(void* const* d_in, const int* in_sizes, int n_in,
                              void* d_out, int out_size, void* d_ws, size_t ws_size,
                              hipStream_t stream)
{
    const float* x = (const float*)d_in[0];
    const float* P[3][8];
    for (int b = 0; b < 3; b++)
        for (int j = 0; j < 8; j++)
            P[b][j] = (const float*)d_in[1 + b * 8 + j];

    float* ws = (float*)d_ws;
    float* stats = ws;                       // 6 stages * 2*NBINS*128 = 49152 f32
    u16*  wswz0  = (u16*)(stats + 49152);    // 2048 u16
    u16*  wswz1  = wswz0 + 2048;             // 8192 u16
    u16*  wswz2  = wswz1 + 8192;             // 16384 u16
    u16*  A      = wswz2 + 16384;            // up to 12,845,056 bf16
    u16*  B      = A + 13000000;             // up to 25,690,112 bf16

    float* out = (float*)d_out;

    prep_k<<<13, 256, 0, stream>>>(P[0][4], P[1][4], P[2][4], wswz0, wswz1, wswz2, stats);

#define BSUM(i) (stats + (i) * 8192)
#define BSQ(i)  (stats + (i) * 8192 + 4096)

    const float inv1 = 1.f / (32.f * 12544.f);
    const float inv2 = 1.f / (32.f * 3136.f);

    // ---- block 0: dw 32ch 112x112 (fp32 in) ; pw 32->64 ----
    dwlds_k<112, 32, false, 16, 120, float><<<7168, 256, 0, stream>>>(
        x, A, P[0][0], P[0][1], nullptr, nullptr, nullptr, nullptr, 0.f,
        BSUM(0), BSQ(0));

    pwmfma_k<32, 64, 12544><<<6272, 256, 0, stream>>>(
        A, B, wswz0, P[0][5], P[0][2], P[0][3], BSUM(0), BSQ(0), inv1,
        BSUM(1), BSQ(1));

    // ---- block 1: dw 64ch stride 2 112->56 ; pw 64->128 ----
    dwtile2_k<112, 56, 64, 4><<<1568, 256, 0, stream>>>(
        B, A, P[1][0], P[1][1], P[0][6], P[0][7], BSUM(1), BSQ(1), inv1,
        BSUM(2), BSQ(2));

    pwmfma_k<64, 128, 3136><<<1568, 256, 0, stream>>>(
        A, B, wswz1, P[1][5], P[1][2], P[1][3], BSUM(2), BSQ(2), inv2,
        BSUM(3), BSQ(3));

    // ---- block 2: dw 128ch 56x56 ; pw 128->128 ----
    dwlds_k<56, 128, true, 28, 68, u16><<<8192, 256, 0, stream>>>(
        B, A, P[2][0], P[2][1], P[1][6], P[1][7], BSUM(3), BSQ(3), inv2,
        BSUM(4), BSQ(4));

    pwmfma_k<128, 128, 3136><<<1568, 256, 0, stream>>>(
        A, B, wswz2, P[2][5], P[2][2], P[2][3], BSUM(4), BSQ(4), inv2,
        BSUM(5), BSQ(5));

    // ---- final: BN+ReLU + global average pool ----
    avgpool_k<3136, 128><<<4096, 256, 0, stream>>>(
        B, P[2][6], P[2][7], BSUM(5), BSQ(5), inv2, out);

#undef BSUM
#undef BSQ
}